// Round 2
// baseline (708.015 us; speedup 1.0000x reference)
//
#include <hip/hip_runtime.h>
#include <hip/hip_bf16.h>

typedef __hip_bfloat16 bf16;

// ===== INSTRUMENTATION BUILD: REP=8 in-kernel repeats to expose per-kernel durations
// ===== in the rocprof top-5 table (fills sit at ~43us; 8x pushes real kernels past them).
// ===== All wrapped bodies are idempotent. Remove REP next round.
#define REP 8

static __device__ __forceinline__ unsigned short f2us(float f) {
    union { float f; unsigned int i; } c; c.f = f;
    unsigned int r = c.i + 0x7FFF + ((c.i >> 16) & 1);   // round-to-nearest-even
    return (unsigned short)(r >> 16);
}

// wave-0 probe: is the float input stored as f32 (vs bf16)?
static __device__ __forceinline__ int probe_isf32(const unsigned short* xr, int* sflag) {
    int tid = threadIdx.x;
    if (tid < 64) {
        int bad = 0;
        for (int i = tid; i < 1024; i += 64) {
            int ex = (xr[2 * i] >> 7) & 0xFF;
            if (ex < 110 || ex > 135) bad++;
        }
#pragma unroll
        for (int m = 32; m >= 1; m >>= 1) bad += __shfl_xor(bad, m);
        if (tid == 0) *sflag = (bad > 256) ? 1 : 0;
    }
    __syncthreads();
    return *sflag;
}

static __device__ __forceinline__ int ld_edge(const int* er, size_t i, int idx64) {
    return idx64 ? er[2 * i] : er[i];
}

#define BSH 9
#define BMASK 511
#define CUR_STRIDE 16   // bucket cursors padded to 64B to avoid same-line atomic serialization

// ---------------- canonicalization + Wcat/Mfac pack + bcur zero (fused) ----------------

struct CvtArgs { const void* p[18]; int sz[18]; };

static __device__ __forceinline__ float cvt_elem(const void* p, int off, int isf32) {
    return isf32 ? ((const float*)p)[off] : __bfloat162float(((const bf16*)p)[off]);
}

// blocks 0..nbconv-1: convert weight inputs to f32 canon.
// block nbconv: Wcat[32][32], bcat, Mfac (l1 attention factorization), zero padded bcur, flag.
__global__ __launch_bounds__(256) void k_convert(CvtArgs a, const unsigned short* __restrict__ xraw,
                                                 float* __restrict__ dst, int total,
                                                 int nbconv, float* __restrict__ Wcat,
                                                 float* __restrict__ bcat, float* __restrict__ Mfac,
                                                 int* __restrict__ bcur) {
    __shared__ int sflag;
    int isf32 = probe_isf32(xraw, &sflag);
    int tid = threadIdx.x;
    if ((int)blockIdx.x == nbconv) {
        // seg map (input i -> p[i-2]): 0=W1 1=att_src1 2=att_dst1 3=b1 4=W2l 5=b2l 6=W2r 7=b2r
        // 8=att2 9=b2 10=Wq 11=bq 12=Wk 13=bk 14=Wv 15=bv 16=Wskip 17=bskip
#pragma unroll
        for (int t4 = 0; t4 < 4; ++t4) {
            int idx = t4 * 256 + tid;           // 0..1023
            int c = idx & 31, g = c >> 3, cc = c & 7, kk = idx >> 5;
            const void* Wg = (g == 0) ? a.p[10] : (g == 1) ? a.p[16] : (g == 2) ? a.p[12] : a.p[14];
            Wcat[idx] = (cc < 7) ? cvt_elem(Wg, kk * 7 + cc, isf32) : 0.f;
        }
        if (tid < 32) {
            int g = tid >> 3, cc = tid & 7;
            const void* Bg = (g == 0) ? a.p[11] : (g == 1) ? a.p[17] : (g == 2) ? a.p[13] : a.p[15];
            bcat[tid] = (cc < 7) ? cvt_elem(Bg, cc, isf32) : 0.f;
        }
        // Mfac: Ms[k][H] = sum_c W1[k][16H+c]*att_src1[H][c]; Md likewise with att_dst1.
        // layout: Mfac[which*16 + k*4 + H]
        if (tid < 24) {
            int which = tid / 12;
            int r = tid % 12; int k = r >> 2, H = r & 3;
            const void* W1p = a.p[0];
            const void* ap = which ? a.p[2] : a.p[1];
            float s = 0.f;
            for (int c = 0; c < 16; ++c)
                s += cvt_elem(W1p, k * 64 + H * 16 + c, isf32) * cvt_elem(ap, H * 16 + c, isf32);
            Mfac[which * 16 + k * 4 + H] = s;
        }
        for (int i = tid; i < 512 * CUR_STRIDE + 1; i += 256) bcur[i] = 0;
        if (tid == 0) bcur[512 * CUR_STRIDE] = isf32;   // overwritten by zero loop? no: index == 8192, loop covers it then this sets flag
        __syncthreads();
        if (tid == 0) bcur[512 * CUR_STRIDE] = isf32;
        return;
    }
    int t = blockIdx.x * 256 + tid;
    if (t >= total) return;
    int base = 0, seg = -1, off = 0;
#pragma unroll
    for (int i = 0; i < 18; i++) {
        if (seg < 0 && t < base + a.sz[i]) { seg = i; off = t - base; }
        base += a.sz[i];
    }
    dst[t] = cvt_elem(a.p[seg], off, isf32);
}

// ---------------- bucketed CSR build (512-node buckets; packed bkt) ----------------

__global__ __launch_bounds__(1024) void k_bscatter(const int* __restrict__ er,
                                                   int* __restrict__ bcur, int* __restrict__ bkt,
                                                   int E, int NB, int C) {
    __shared__ int cnt[512];
    __shared__ int res[512];
    __shared__ int sflag;
    int tid = threadIdx.x;
    if (tid < 64) {
        int lim = (E < 1024) ? E : 1024;
        int nz = 0;
        for (int i = tid; i < lim; i += 64) if (er[2 * i + 1] != 0) nz++;
#pragma unroll
        for (int m = 32; m >= 1; m >>= 1) nz += __shfl_xor(nz, m);
        if (tid == 0) sflag = (nz < ((E < 1024 ? E : 1024) >> 1)) ? 1 : 0;
    }
    if (tid < 512) cnt[tid] = 0;
    __syncthreads();
    int idx64 = sflag;
    int e0 = blockIdx.x * 4096 + tid * 4;
    int sv[4], dv[4];
    bool val[4];
    bool fast = (e0 + 4 <= E) && ((E & 3) == 0);
    if (fast) {
        const int4* p4 = (const int4*)er;
        if (idx64) {
            int4 u0 = p4[e0 >> 1], u1 = p4[(e0 >> 1) + 1];
            int4 w0 = p4[(E + e0) >> 1], w1 = p4[((E + e0) >> 1) + 1];
            sv[0] = u0.x; sv[1] = u0.z; sv[2] = u1.x; sv[3] = u1.z;
            dv[0] = w0.x; dv[1] = w0.z; dv[2] = w1.x; dv[3] = w1.z;
        } else {
            int4 u = p4[e0 >> 2];
            int4 w = p4[(E + e0) >> 2];
            sv[0] = u.x; sv[1] = u.y; sv[2] = u.z; sv[3] = u.w;
            dv[0] = w.x; dv[1] = w.y; dv[2] = w.z; dv[3] = w.w;
        }
#pragma unroll
        for (int k = 0; k < 4; ++k) val[k] = true;
    } else {
#pragma unroll
        for (int k = 0; k < 4; ++k) {
            int e = e0 + k;
            val[k] = (e < E);
            if (val[k]) {
                sv[k] = ld_edge(er, (size_t)e, idx64);
                dv[k] = ld_edge(er, (size_t)E + e, idx64);
            }
        }
    }
    int pk[4], bv[4];
#pragma unroll
    for (int k = 0; k < 4; ++k) {
        if (val[k]) {
            bv[k] = dv[k] >> BSH;
            pk[k] = (sv[k] << BSH) | (dv[k] & BMASK);
            atomicAdd(&cnt[bv[k]], 1);
        }
    }
    __syncthreads();
    if (tid < NB) {
        int c = cnt[tid];
        res[tid] = c ? atomicAdd(&bcur[tid * CUR_STRIDE], c) : 0;
        cnt[tid] = 0;
    }
    __syncthreads();
#pragma unroll
    for (int k = 0; k < 4; ++k) {
        if (val[k]) {
            int r = res[bv[k]] + atomicAdd(&cnt[bv[k]], 1);
            if (r < C) bkt[(size_t)bv[k] * C + r] = pk[k];
        }
    }
}

// blocks < NB: per-bucket indeg count + scan -> off2; scatter src -> bucket-strided csr.
// blocks >= NB: layer-1 transform (M-factored): axs = {x.Ms, x, 0}, ad1 = x.Md.
__global__ __launch_bounds__(512) void k_bbuild_l1t(const int* __restrict__ bkt, const int* __restrict__ bcur,
                                                    int2* __restrict__ off2, int* __restrict__ csr,
                                                    const void* __restrict__ xr, const int* __restrict__ flagp,
                                                    const float* __restrict__ Mfac,
                                                    float* __restrict__ axs, float* __restrict__ ad1,
                                                    int N, int NB, int C) {
    int tid = threadIdx.x;
    if ((int)blockIdx.x < NB) {
        __shared__ int sm[512];
        int b = blockIdx.x;
        size_t base = (size_t)b * C;
        int m = bcur[b * CUR_STRIDE]; if (m > C) m = C;
        const int* bp = bkt + base;
        for (int rep = 0; rep < REP; ++rep) {
            sm[tid] = 0;
            __syncthreads();
            for (int i = tid; i < m; i += 512) atomicAdd(&sm[bp[i] & BMASK], 1);
            __syncthreads();
            int v = sm[tid];
            for (int d = 1; d < 512; d <<= 1) {
                int t = (tid >= d) ? sm[tid - d] : 0;
                __syncthreads();
                sm[tid] += t;
                __syncthreads();
            }
            int excl = sm[tid] - v;
            int node = (b << BSH) + tid;
            if (node < N) off2[node] = make_int2((int)base + excl, (int)base + excl + v);
            __syncthreads();
            sm[tid] = excl;
            __syncthreads();
            for (int i = tid; i < m; i += 512) {
                int p = bp[i];
                int r = atomicAdd(&sm[p & BMASK], 1);
                csr[base + r] = p >> BSH;
            }
            __syncthreads();
        }
    } else {
        int isf32 = *flagp;
        float ms[12], md[12];
#pragma unroll
        for (int i = 0; i < 12; ++i) { ms[i] = Mfac[i]; md[i] = Mfac[16 + i]; }
        int node = ((int)blockIdx.x - NB) * 512 + tid;
        for (int rep = 0; rep < REP; ++rep) {
            if (node < N) {
                float x0 = cvt_elem(xr, node * 3 + 0, isf32);
                float x1 = cvt_elem(xr, node * 3 + 1, isf32);
                float x2 = cvt_elem(xr, node * 3 + 2, isf32);
                float4 as, ad;
                as.x = x0 * ms[0] + x1 * ms[4] + x2 * ms[8];
                as.y = x0 * ms[1] + x1 * ms[5] + x2 * ms[9];
                as.z = x0 * ms[2] + x1 * ms[6] + x2 * ms[10];
                as.w = x0 * ms[3] + x1 * ms[7] + x2 * ms[11];
                ad.x = x0 * md[0] + x1 * md[4] + x2 * md[8];
                ad.y = x0 * md[1] + x1 * md[5] + x2 * md[9];
                ad.z = x0 * md[2] + x1 * md[6] + x2 * md[10];
                ad.w = x0 * md[3] + x1 * md[7] + x2 * md[11];
                *(float4*)&axs[(size_t)node * 8] = as;
                *(float4*)&axs[(size_t)node * 8 + 4] = make_float4(x0, x1, x2, 0.f);
                *(float4*)&ad1[(size_t)node * 4] = ad;
            }
        }
    }
}

// ---------------- Layer 1 agg: GATConv(3, 16, heads=4) ----------------
// Edge-parallel: 16 lanes/node; 2-deep prefetch (next csr + next 32B axs row in flight).

__global__ __launch_bounds__(256) void k_l1_agg(const float* __restrict__ axs,
                                                const float4* __restrict__ ad4p, const int2* __restrict__ off2,
                                                const int* __restrict__ csr, const float* __restrict__ W1,
                                                const float* __restrict__ b1,
                                                float* __restrict__ x1, int N) {
    int tid = threadIdx.x;
    int node = blockIdx.x * 16 + (tid >> 4);
    if (node >= N) return;
    int sl = tid & 15;
    int lane = tid & 63;
    int lb = lane & 48;

    float4 ad = ad4p[node];
    int2 ee = off2[node];

    for (int rep = 0; rep < REP; ++rep) {
        float v[16];
#pragma unroll
        for (int i = 0; i < 16; ++i) v[i] = 0.f;

        int jj = ee.x + sl;
        int sN = (jj < ee.y) ? csr[jj] : node;
        const float4* rpN = (const float4*)(axs + (size_t)sN * 8);
        float4 aN = rpN[0], xN = rpN[1];
        while (jj < ee.y) {
            float4 a = aN, xv = xN;
            int jn = jj + 16;
            int s2 = (jn < ee.y) ? csr[jn] : node;
            const float4* rp2 = (const float4*)(axs + (size_t)s2 * 8);
            aN = rp2[0]; xN = rp2[1];
            float z0 = a.x + ad.x, z1 = a.y + ad.y, z2 = a.z + ad.z, z3 = a.w + ad.w;
            z0 = (z0 > 0.f) ? z0 : 0.2f * z0;
            z1 = (z1 > 0.f) ? z1 : 0.2f * z1;
            z2 = (z2 > 0.f) ? z2 : 0.2f * z2;
            z3 = (z3 > 0.f) ? z3 : 0.2f * z3;
            float w0 = __expf(z0), w1 = __expf(z1), w2 = __expf(z2), w3 = __expf(z3);
            v[0] += w0 * xv.x; v[1] += w0 * xv.y; v[2]  += w0 * xv.z; v[3]  += w0;
            v[4] += w1 * xv.x; v[5] += w1 * xv.y; v[6]  += w1 * xv.z; v[7]  += w1;
            v[8] += w2 * xv.x; v[9] += w2 * xv.y; v[10] += w2 * xv.z; v[11] += w2;
            v[12] += w3 * xv.x; v[13] += w3 * xv.y; v[14] += w3 * xv.z; v[15] += w3;
            jj = jn;
        }

#pragma unroll
        for (int d = 8; d >= 1; d >>= 1) {
#pragma unroll
            for (int i = 0; i < 16; ++i) {
                if (i < d) {
                    float a = v[i], b = v[i + d];
                    float send = (sl & d) ? a : b;
                    float recv = __shfl_xor(send, d);
                    v[i] = ((sl & d) ? b : a) + recv;
                }
            }
        }
        float r = v[0];

        float agx[4], agy[4], agz[4], dn[4];
#pragma unroll
        for (int h = 0; h < 4; ++h) {
            agx[h] = __shfl(r, lb + 4 * h + 0);
            agy[h] = __shfl(r, lb + 4 * h + 1);
            agz[h] = __shfl(r, lb + 4 * h + 2);
            dn[h]  = __shfl(r, lb + 4 * h + 3);
        }

        {
            const float4* rp = (const float4*)(axs + (size_t)node * 8);
            float4 a = rp[0];
            float4 xv = rp[1];
            float z0 = a.x + ad.x, z1 = a.y + ad.y, z2 = a.z + ad.z, z3 = a.w + ad.w;
            z0 = (z0 > 0.f) ? z0 : 0.2f * z0;
            z1 = (z1 > 0.f) ? z1 : 0.2f * z1;
            z2 = (z2 > 0.f) ? z2 : 0.2f * z2;
            z3 = (z3 > 0.f) ? z3 : 0.2f * z3;
            float w0 = __expf(z0), w1 = __expf(z1), w2 = __expf(z2), w3 = __expf(z3);
            agx[0] += w0 * xv.x; agy[0] += w0 * xv.y; agz[0] += w0 * xv.z; dn[0] += w0;
            agx[1] += w1 * xv.x; agy[1] += w1 * xv.y; agz[1] += w1 * xv.z; dn[1] += w1;
            agx[2] += w2 * xv.x; agy[2] += w2 * xv.y; agz[2] += w2 * xv.z; dn[2] += w2;
            agx[3] += w3 * xv.x; agy[3] += w3 * xv.y; agz[3] += w3 * xv.z; dn[3] += w3;
        }

#pragma unroll
        for (int h = 0; h < 4; ++h) {
            int j = h * 16 + sl;
            float inv = 1.f / (dn[h] + 1e-16f);
            float o = (agx[h] * W1[j] + agy[h] * W1[64 + j] + agz[h] * W1[128 + j]) * inv + b1[j];
            x1[(size_t)node * 64 + j] = (o > 0.f) ? o : 0.f;
        }
    }
}

// ---------------- Layer 2: GATv2Conv(64, 16, heads=2) ----------------

__global__ __launch_bounds__(256) void k_l2_transform(const float* __restrict__ x1,
                                                      const float* __restrict__ W2l, const float* __restrict__ b2l,
                                                      const float* __restrict__ W2r, const float* __restrict__ b2r,
                                                      unsigned short* __restrict__ hlb, float* __restrict__ hr, int N) {
    __shared__ float xs[64 * 68];
    int t = threadIdx.x;
    int node0 = blockIdx.x * 64;
    int nrem = N - node0; if (nrem > 64) nrem = 64;
    const float4* xg = (const float4*)x1;
    for (int rep = 0; rep < REP; ++rep) {
#pragma unroll
        for (int it = 0; it < 4; ++it) {
            int id = it * 256 + t;
            int row = id >> 4, c4 = id & 15;
            float4 v = make_float4(0.f, 0.f, 0.f, 0.f);
            if (row < nrem) v = xg[(size_t)(node0 + row) * 16 + c4];
            *(float4*)&xs[row * 68 + c4 * 4] = v;
        }
        __syncthreads();
        int nt = t >> 4;
        int jt = t & 15;
        int jq = jt & 7;
        int jc = jq * 4;
        const float4* W4 = (const float4*)((jt < 8) ? W2l : W2r);
        const float4* B4 = (const float4*)((jt < 8) ? b2l : b2r);
        float4 bb = B4[jq];
        float4 acc[4];
#pragma unroll
        for (int i = 0; i < 4; ++i) acc[i] = bb;
#pragma unroll 2
        for (int k4 = 0; k4 < 16; ++k4) {
            float4 w0 = W4[(k4 * 4 + 0) * 8 + jq];
            float4 w1 = W4[(k4 * 4 + 1) * 8 + jq];
            float4 w2 = W4[(k4 * 4 + 2) * 8 + jq];
            float4 w3 = W4[(k4 * 4 + 3) * 8 + jq];
#pragma unroll
            for (int i = 0; i < 4; ++i) {
                float4 xv = *(const float4*)&xs[(nt + i * 16) * 68 + k4 * 4];
                acc[i].x += xv.x * w0.x + xv.y * w1.x + xv.z * w2.x + xv.w * w3.x;
                acc[i].y += xv.x * w0.y + xv.y * w1.y + xv.z * w2.y + xv.w * w3.y;
                acc[i].z += xv.x * w0.z + xv.y * w1.z + xv.z * w2.z + xv.w * w3.z;
                acc[i].w += xv.x * w0.w + xv.y * w1.w + xv.z * w2.w + xv.w * w3.w;
            }
        }
#pragma unroll
        for (int i = 0; i < 4; ++i) {
            int row = nt + i * 16;
            if (row < nrem) {
                size_t node = node0 + row;
                if (jt < 8) {
                    uint2 p;
                    p.x = (unsigned)f2us(acc[i].x) | ((unsigned)f2us(acc[i].y) << 16);
                    p.y = (unsigned)f2us(acc[i].z) | ((unsigned)f2us(acc[i].w) << 16);
                    *(uint2*)&hlb[node * 32 + jc] = p;
                } else {
                    *(float4*)&hr[node * 32 + jc] = acc[i];
                }
            }
        }
        __syncthreads();
    }
}

// Edge-parallel, cooperative gather: 16 lanes/node = 4 edge slots x 4 channel-quarters.
// 2-deep prefetch: next csr + next 16B row quarter issued before current compute.
__global__ __launch_bounds__(256) void k_l2_agg(const unsigned short* __restrict__ hlb, const float* __restrict__ hr,
                                                const float* __restrict__ att2, const float* __restrict__ b2,
                                                const int2* __restrict__ off2, const int* __restrict__ csr,
                                                float* __restrict__ x2, int N) {
    int tid = threadIdx.x;
    int node = blockIdx.x * 16 + (tid >> 4);
    if (node >= N) return;
    int sl = tid & 15;
    int g = sl & 3;
    int slot = sl >> 2;

    float hrq[8], atq[8];
    {
        const float4* h4 = (const float4*)(hr + (size_t)node * 32 + g * 8);
        float4 h0 = h4[0], h1 = h4[1];
        hrq[0] = h0.x; hrq[1] = h0.y; hrq[2] = h0.z; hrq[3] = h0.w;
        hrq[4] = h1.x; hrq[5] = h1.y; hrq[6] = h1.z; hrq[7] = h1.w;
        const float4* a4 = (const float4*)(att2 + g * 8);
        float4 a0 = a4[0], a1 = a4[1];
        atq[0] = a0.x; atq[1] = a0.y; atq[2] = a0.z; atq[3] = a0.w;
        atq[4] = a1.x; atq[5] = a1.y; atq[6] = a1.z; atq[7] = a1.w;
    }
    int2 ee = off2[node];

    for (int rep = 0; rep < REP; ++rep) {
        float acc[8];
#pragma unroll
        for (int j = 0; j < 8; ++j) acc[j] = 0.f;
        float den = 0.f;

        int jj = ee.x + slot;
        int sN = (jj < ee.y) ? csr[jj] : node;
        uint4 uN = *(const uint4*)(hlb + (size_t)sN * 32 + g * 8);
        while (jj < ee.y) {
            uint4 u = uN;
            int jn = jj + 4;
            int s2 = (jn < ee.y) ? csr[jn] : node;
            uN = *(const uint4*)(hlb + (size_t)s2 * 32 + g * 8);
            unsigned uu[4] = {u.x, u.y, u.z, u.w};
            float hlv[8];
#pragma unroll
            for (int q = 0; q < 4; ++q) {
                hlv[2 * q]     = __uint_as_float(uu[q] << 16);
                hlv[2 * q + 1] = __uint_as_float(uu[q] & 0xFFFF0000u);
            }
            float t = 0.f;
#pragma unroll
            for (int j = 0; j < 8; ++j) {
                float e = hlv[j] + hrq[j];
                e = fmaxf(e, 0.2f * e);
                t += atq[j] * e;
            }
            t += __shfl_xor(t, 1);
            float w = __expf(t);
            den += w;
#pragma unroll
            for (int j = 0; j < 8; ++j) acc[j] += w * hlv[j];
            jj = jn;
        }

        if (slot == 0) {
            uint4 u = *(const uint4*)(hlb + (size_t)node * 32 + g * 8);
            unsigned uu[4] = {u.x, u.y, u.z, u.w};
            float hlv[8];
#pragma unroll
            for (int q = 0; q < 4; ++q) {
                hlv[2 * q]     = __uint_as_float(uu[q] << 16);
                hlv[2 * q + 1] = __uint_as_float(uu[q] & 0xFFFF0000u);
            }
            float t = 0.f;
#pragma unroll
            for (int j = 0; j < 8; ++j) {
                float e = hlv[j] + hrq[j];
                e = fmaxf(e, 0.2f * e);
                t += atq[j] * e;
            }
            t += __shfl_xor(t, 1);
            float w = __expf(t);
            den += w;
#pragma unroll
            for (int j = 0; j < 8; ++j) acc[j] += w * hlv[j];
        }

#pragma unroll
        for (int d = 4; d <= 8; d <<= 1) {
#pragma unroll
            for (int j = 0; j < 8; ++j) acc[j] += __shfl_xor(acc[j], d);
            den += __shfl_xor(den, d);
        }

        if (slot < 2) {
            float inv = 1.f / (den + 1e-16f);
            int c = g * 8 + slot * 4;
            float4 bb = *(const float4*)(b2 + c);
            float o0 = slot ? acc[4] : acc[0];
            float o1 = slot ? acc[5] : acc[1];
            float o2 = slot ? acc[6] : acc[2];
            float o3 = slot ? acc[7] : acc[3];
            *(float4*)&x2[(size_t)node * 32 + c] =
                make_float4(o0 * inv + bb.x, o1 * inv + bb.y, o2 * inv + bb.z, o3 * inv + bb.w);
        }
    }
}

// ---------------- Layer 3: TransformerConv(32, 7, heads=1) ----------------

__global__ __launch_bounds__(256) void k_l3_transform(const float* __restrict__ x2,
                                                      const float4* __restrict__ Wc4, const float4* __restrict__ bc4,
                                                      float* __restrict__ QS, unsigned short* __restrict__ KVb, int N) {
    __shared__ float xs[128 * 36];
    int t = threadIdx.x;
    int node0 = blockIdx.x * 128;
    int nrem = N - node0; if (nrem > 128) nrem = 128;
    const float4* xg = (const float4*)x2;
    for (int rep = 0; rep < REP; ++rep) {
#pragma unroll
        for (int it = 0; it < 4; ++it) {
            int id = it * 256 + t;
            int row = id >> 3, c4 = id & 7;
            float4 v = make_float4(0.f, 0.f, 0.f, 0.f);
            if (row < nrem) v = xg[(size_t)(node0 + row) * 8 + c4];
            *(float4*)&xs[row * 36 + c4 * 4] = v;
        }
        __syncthreads();
        int nt = t >> 3;
        int jt = t & 7;
        float4 bb = bc4[jt];
        float4 acc[4];
#pragma unroll
        for (int i = 0; i < 4; ++i) acc[i] = bb;
#pragma unroll 2
        for (int k4 = 0; k4 < 8; ++k4) {
            float4 w0 = Wc4[(k4 * 4 + 0) * 8 + jt];
            float4 w1 = Wc4[(k4 * 4 + 1) * 8 + jt];
            float4 w2 = Wc4[(k4 * 4 + 2) * 8 + jt];
            float4 w3 = Wc4[(k4 * 4 + 3) * 8 + jt];
#pragma unroll
            for (int i = 0; i < 4; ++i) {
                float4 xv = *(const float4*)&xs[(nt + i * 32) * 36 + k4 * 4];
                acc[i].x += xv.x * w0.x + xv.y * w1.x + xv.z * w2.x + xv.w * w3.x;
                acc[i].y += xv.x * w0.y + xv.y * w1.y + xv.z * w2.y + xv.w * w3.y;
                acc[i].z += xv.x * w0.z + xv.y * w1.z + xv.z * w2.z + xv.w * w3.z;
                acc[i].w += xv.x * w0.w + xv.y * w1.w + xv.z * w2.w + xv.w * w3.w;
            }
        }
#pragma unroll
        for (int i = 0; i < 4; ++i) {
            int row = nt + i * 32;
            if (row < nrem) {
                size_t node = node0 + row;
                if (jt < 4) {
                    *(float4*)(QS + node * 16 + jt * 4) = acc[i];
                } else {
                    uint2 p;
                    p.x = (unsigned)f2us(acc[i].x) | ((unsigned)f2us(acc[i].y) << 16);
                    p.y = (unsigned)f2us(acc[i].z) | ((unsigned)f2us(acc[i].w) << 16);
                    *(uint2*)&KVb[node * 16 + (size_t)(jt - 4) * 4] = p;
                }
            }
        }
        __syncthreads();
    }
}

// Edge-parallel, pair-cooperative: 16 lanes/node = 8 edge slots x 2 sides; 2-deep prefetch.
__global__ __launch_bounds__(256) void k_l3_agg(const float* __restrict__ QS, const unsigned short* __restrict__ KVb,
                                                const int2* __restrict__ off2, const int* __restrict__ csr,
                                                float* __restrict__ out, int N) {
    int tid = threadIdx.x;
    int node = blockIdx.x * 16 + (tid >> 4);
    if (node >= N) return;
    int sl = tid & 15;
    int side = sl & 1;
    int p = sl >> 1;
    int lane = tid & 63;
    const float scale = 0.3779644730092272f;  // 1/sqrt(7)
    const float4* q4 = (const float4*)(QS + (size_t)node * 16);
    float4 qa = q4[0], qb = q4[1];
    qa.x *= scale; qa.y *= scale; qa.z *= scale; qa.w *= scale;
    qb.x *= scale; qb.y *= scale; qb.z *= scale; qb.w = 0.f;
    int2 ee = off2[node];

    for (int rep = 0; rep < REP; ++rep) {
        float v[8];
#pragma unroll
        for (int i = 0; i < 8; ++i) v[i] = 0.f;

        int jj = ee.x + p;
        int sN = (jj < ee.y) ? csr[jj] : node;
        uint4 uN = *(const uint4*)(KVb + (size_t)sN * 16 + (side << 3));
        while (jj < ee.y) {
            uint4 u = uN;
            int jn = jj + 8;
            int s2 = (jn < ee.y) ? csr[jn] : node;
            uN = *(const uint4*)(KVb + (size_t)s2 * 16 + (side << 3));
            float t = 0.f;
            if (!side) {
                float k0 = __uint_as_float(u.x << 16), k1 = __uint_as_float(u.x & 0xFFFF0000u);
                float k2 = __uint_as_float(u.y << 16), k3 = __uint_as_float(u.y & 0xFFFF0000u);
                float k4 = __uint_as_float(u.z << 16), k5 = __uint_as_float(u.z & 0xFFFF0000u);
                float k6 = __uint_as_float(u.w << 16);
                t = qa.x * k0 + qa.y * k1 + qa.z * k2 + qa.w * k3
                  + qb.x * k4 + qb.y * k5 + qb.z * k6;
            }
            float tf = __shfl_xor(t, 1);
            if (side) {
                float w = __expf(tf);
                v[0] += w * __uint_as_float(u.x << 16);
                v[1] += w * __uint_as_float(u.x & 0xFFFF0000u);
                v[2] += w * __uint_as_float(u.y << 16);
                v[3] += w * __uint_as_float(u.y & 0xFFFF0000u);
                v[4] += w * __uint_as_float(u.z << 16);
                v[5] += w * __uint_as_float(u.z & 0xFFFF0000u);
                v[6] += w * __uint_as_float(u.w << 16);
                v[7] += w;
            }
            jj = jn;
        }

#pragma unroll
        for (int d = 4; d >= 1; d >>= 1) {
#pragma unroll
            for (int i = 0; i < 8; ++i) {
                if (i < d) {
                    float a = v[i], b = v[i + d];
                    float send = (p & d) ? a : b;
                    float recv = __shfl_xor(send, d << 1);
                    v[i] = ((p & d) ? b : a) + recv;
                }
            }
        }
        float r = v[0];
        float den = __shfl(r, (lane & 48) | 15);
        if (side && p < 7) out[(size_t)node * 7 + p] = r / (den + 1e-16f)
                                                       + QS[(size_t)node * 16 + 8 + p];
    }
}

// ---------------- launcher ----------------

extern "C" void kernel_launch(void* const* d_in, const int* in_sizes, int n_in,
                              void* d_out, int out_size, void* d_ws, size_t ws_size,
                              hipStream_t stream) {
    const int* ei = (const int*)d_in[1];
    float* out = (float*)d_out;

    int N = in_sizes[0] / 3;
    int E = in_sizes[1] / 2;
    int NB = (N + BMASK) >> BSH;        // assumed <= 512 (N <= 262144)
    int C = (E + NB - 1) / NB + 4096;

    char* ws = (char*)d_ws;
    size_t o = 0;
    auto take = [&](size_t bytes) -> char* {
        char* p = ws + o;
        o = (o + bytes + 255) & ~(size_t)255;
        return p;
    };
    int total_f = 0;
    for (int i = 2; i < 20; ++i) total_f += in_sizes[i];
    float* canon   = (float*)take((size_t)total_f * 4);
    float* Wcat    = (float*)take(32 * 32 * 4);
    float* bcat    = (float*)take(32 * 4);
    float* Mfac    = (float*)take(32 * 4);
    int2*  off2    = (int2*)take((size_t)N * 8);
    int*   bcur    = (int*)take((512 * CUR_STRIDE + 1) * 4);
    int*   csr     = (int*)take((size_t)NB * C * 4);
    float* bufA    = (float*)take((size_t)N * 64 * 4);  // axs -> hlb|hr -> QS|KVb
    float* ad1     = (float*)take((size_t)N * 4 * 4);
    float* bufB    = (float*)take((size_t)N * 64 * 4);  // bkt -> x1 -> x2
    (void)ws_size; (void)n_in; (void)out_size;

    CvtArgs ca;
    const float* cp[20];
    {
        int off_ = 0, k = 0;
        for (int i = 0; i < 20; ++i) {
            if (i < 2) { cp[i] = nullptr; continue; }
            ca.p[k] = d_in[i];
            ca.sz[k] = in_sizes[i];
            cp[i] = canon + off_;
            off_ += in_sizes[i];
            ++k;
        }
    }

    int nbconv = (total_f + 255) / 256;
    k_convert<<<nbconv + 1, 256, 0, stream>>>(ca, (const unsigned short*)d_in[0], canon, total_f,
                                              nbconv, Wcat, bcat, Mfac, bcur);
    const int* flagp = bcur + 512 * CUR_STRIDE;

    int* bkt = (int*)bufB;
    int gb = (E + 4095) / 4096;
    k_bscatter<<<gb, 1024, 0, stream>>>(ei, bcur, bkt, E, NB, C);

    float* axs = bufA;
    int nbl1 = (N + 511) >> 9;
    k_bbuild_l1t<<<NB + nbl1, 512, 0, stream>>>(bkt, bcur, off2, csr, d_in[0], flagp, Mfac,
                                                axs, ad1, N, NB, C);

    float* x1 = bufB;
    k_l1_agg<<<(N + 15) / 16, 256, 0, stream>>>(axs, (const float4*)ad1, off2, csr, cp[2], cp[5], x1, N);

    unsigned short* hlb = (unsigned short*)bufA;
    float* hr = bufA + (size_t)N * 16;
    k_l2_transform<<<(N + 63) / 64, 256, 0, stream>>>(x1, cp[6], cp[7], cp[8], cp[9], hlb, hr, N);
    float* x2 = bufB;
    k_l2_agg<<<(N + 15) / 16, 256, 0, stream>>>(hlb, hr, cp[10], cp[11], off2, csr, x2, N);

    float* QS = bufA;
    unsigned short* KVb = (unsigned short*)(bufA + (size_t)N * 16);
    k_l3_transform<<<(N + 127) / 128, 256, 0, stream>>>(x2, (const float4*)Wcat, (const float4*)bcat,
                                                        QS, KVb, N);
    k_l3_agg<<<(N + 15) / 16, 256, 0, stream>>>(QS, KVb, off2, csr, out, N);
}

// Round 3
// 572.877 us; speedup vs baseline: 1.2359x; 1.2359x over previous
//
#include <hip/hip_runtime.h>
#include <hip/hip_bf16.h>

typedef __hip_bfloat16 bf16;

// ===== INSTRUMENTATION: REPU=8 on the five unmeasured kernels (l2_agg known: 21.7us).
// ===== Solves the per-kernel time distribution one name per round via the top-5 table.
#define REPU 8

static __device__ __forceinline__ unsigned short f2us(float f) {
    union { float f; unsigned int i; } c; c.f = f;
    unsigned int r = c.i + 0x7FFF + ((c.i >> 16) & 1);   // round-to-nearest-even
    return (unsigned short)(r >> 16);
}

// wave-0 probe: is the float input stored as f32 (vs bf16)?
static __device__ __forceinline__ int probe_isf32(const unsigned short* xr, int* sflag) {
    int tid = threadIdx.x;
    if (tid < 64) {
        int bad = 0;
        for (int i = tid; i < 1024; i += 64) {
            int ex = (xr[2 * i] >> 7) & 0xFF;
            if (ex < 110 || ex > 135) bad++;
        }
#pragma unroll
        for (int m = 32; m >= 1; m >>= 1) bad += __shfl_xor(bad, m);
        if (tid == 0) *sflag = (bad > 256) ? 1 : 0;
    }
    __syncthreads();
    return *sflag;
}

static __device__ __forceinline__ int ld_edge(const int* er, size_t i, int idx64) {
    return idx64 ? er[2 * i] : er[i];
}

#define BSH 9
#define BMASK 511
#define CUR_STRIDE 16   // bucket cursors padded to 64B: no same-line atomic serialization

// ---------------- canonicalization + Wcat/Mfac pack + bcur zero (fused) ----------------

struct CvtArgs { const void* p[18]; int sz[18]; };

static __device__ __forceinline__ float cvt_elem(const void* p, int off, int isf32) {
    return isf32 ? ((const float*)p)[off] : __bfloat162float(((const bf16*)p)[off]);
}

__global__ __launch_bounds__(256) void k_convert(CvtArgs a, const unsigned short* __restrict__ xraw,
                                                 float* __restrict__ dst, int total,
                                                 int nbconv, float* __restrict__ Wcat,
                                                 float* __restrict__ bcat, float* __restrict__ Mfac,
                                                 int* __restrict__ bcur) {
    __shared__ int sflag;
    int isf32 = probe_isf32(xraw, &sflag);
    int tid = threadIdx.x;
    if ((int)blockIdx.x == nbconv) {
        // p-map: 0=W1 1=att_src1 2=att_dst1 3=b1 4=W2l 5=b2l 6=W2r 7=b2r 8=att2 9=b2
        //        10=Wq 11=bq 12=Wk 13=bk 14=Wv 15=bv 16=Wskip 17=bskip
#pragma unroll
        for (int t4 = 0; t4 < 4; ++t4) {
            int idx = t4 * 256 + tid;           // 0..1023
            int c = idx & 31, g = c >> 3, cc = c & 7, kk = idx >> 5;
            const void* Wg = (g == 0) ? a.p[10] : (g == 1) ? a.p[16] : (g == 2) ? a.p[12] : a.p[14];
            Wcat[idx] = (cc < 7) ? cvt_elem(Wg, kk * 7 + cc, isf32) : 0.f;
        }
        if (tid < 32) {
            int g = tid >> 3, cc = tid & 7;
            const void* Bg = (g == 0) ? a.p[11] : (g == 1) ? a.p[17] : (g == 2) ? a.p[13] : a.p[15];
            bcat[tid] = (cc < 7) ? cvt_elem(Bg, cc, isf32) : 0.f;
        }
        // Mfac: Ms[k][H] = sum_c W1[k][16H+c]*att_src1[H][c]; Md with att_dst1.
        if (tid < 24) {
            int which = tid / 12;
            int r = tid % 12; int k = r >> 2, H = r & 3;
            const void* W1p = a.p[0];
            const void* ap = which ? a.p[2] : a.p[1];
            float s = 0.f;
            for (int c = 0; c < 16; ++c)
                s += cvt_elem(W1p, k * 64 + H * 16 + c, isf32) * cvt_elem(ap, H * 16 + c, isf32);
            Mfac[which * 16 + k * 4 + H] = s;
        }
        for (int i = tid; i < 512 * CUR_STRIDE + 1; i += 256) bcur[i] = 0;
        __syncthreads();
        if (tid == 0) bcur[512 * CUR_STRIDE] = isf32;
        return;
    }
    int t = blockIdx.x * 256 + tid;
    if (t >= total) return;
    int base = 0, seg = -1, off = 0;
#pragma unroll
    for (int i = 0; i < 18; i++) {
        if (seg < 0 && t < base + a.sz[i]) { seg = i; off = t - base; }
        base += a.sz[i];
    }
    dst[t] = cvt_elem(a.p[seg], off, isf32);
}

// ---------------- bucketed CSR build (512-node buckets; packed bkt) ----------------

__global__ __launch_bounds__(1024) void k_bscatter(const int* __restrict__ er,
                                                   int* __restrict__ bcur, int* __restrict__ bkt,
                                                   int E, int NB, int C) {
    __shared__ int cnt[512];
    __shared__ int res[512];
    __shared__ int sflag;
    int tid = threadIdx.x;
    if (tid < 64) {
        int lim = (E < 1024) ? E : 1024;
        int nz = 0;
        for (int i = tid; i < lim; i += 64) if (er[2 * i + 1] != 0) nz++;
#pragma unroll
        for (int m = 32; m >= 1; m >>= 1) nz += __shfl_xor(nz, m);
        if (tid == 0) sflag = (nz < ((E < 1024 ? E : 1024) >> 1)) ? 1 : 0;
    }
    if (tid < 512) cnt[tid] = 0;
    __syncthreads();
    int idx64 = sflag;
    int e0 = blockIdx.x * 4096 + tid * 4;
    int sv[4], dv[4];
    bool val[4];
    bool fast = (e0 + 4 <= E) && ((E & 3) == 0);
    if (fast) {
        const int4* p4 = (const int4*)er;
        if (idx64) {
            int4 u0 = p4[e0 >> 1], u1 = p4[(e0 >> 1) + 1];
            int4 w0 = p4[(E + e0) >> 1], w1 = p4[((E + e0) >> 1) + 1];
            sv[0] = u0.x; sv[1] = u0.z; sv[2] = u1.x; sv[3] = u1.z;
            dv[0] = w0.x; dv[1] = w0.z; dv[2] = w1.x; dv[3] = w1.z;
        } else {
            int4 u = p4[e0 >> 2];
            int4 w = p4[(E + e0) >> 2];
            sv[0] = u.x; sv[1] = u.y; sv[2] = u.z; sv[3] = u.w;
            dv[0] = w.x; dv[1] = w.y; dv[2] = w.z; dv[3] = w.w;
        }
#pragma unroll
        for (int k = 0; k < 4; ++k) val[k] = true;
    } else {
#pragma unroll
        for (int k = 0; k < 4; ++k) {
            int e = e0 + k;
            val[k] = (e < E);
            if (val[k]) {
                sv[k] = ld_edge(er, (size_t)e, idx64);
                dv[k] = ld_edge(er, (size_t)E + e, idx64);
            }
        }
    }
    int pk[4], bv[4];
#pragma unroll
    for (int k = 0; k < 4; ++k) {
        if (val[k]) {
            bv[k] = dv[k] >> BSH;
            pk[k] = (sv[k] << BSH) | (dv[k] & BMASK);
            atomicAdd(&cnt[bv[k]], 1);
        }
    }
    __syncthreads();
    if (tid < NB) {
        int c = cnt[tid];
        res[tid] = c ? atomicAdd(&bcur[tid * CUR_STRIDE], c) : 0;
        cnt[tid] = 0;
    }
    __syncthreads();
#pragma unroll
    for (int k = 0; k < 4; ++k) {
        if (val[k]) {
            int r = res[bv[k]] + atomicAdd(&cnt[bv[k]], 1);
            if (r < C) bkt[(size_t)bv[k] * C + r] = pk[k];
        }
    }
}

// blocks < NB: per-bucket indeg count + hierarchical wave-scan -> off2; scatter src -> csr.
// blocks >= NB: layer-1 transform (M-factored): axs = {x.Ms, x, 0}, ad1 = x.Md.
__global__ __launch_bounds__(512) void k_bbuild_l1t(const int* __restrict__ bkt, const int* __restrict__ bcur,
                                                    int2* __restrict__ off2, int* __restrict__ csr,
                                                    const void* __restrict__ xr, const int* __restrict__ flagp,
                                                    const float* __restrict__ Mfac,
                                                    float* __restrict__ axs, float* __restrict__ ad1,
                                                    int N, int NB, int C) {
    int tid = threadIdx.x;
    if ((int)blockIdx.x < NB) {
        __shared__ int sm[512];
        __shared__ int wsum[16];
        int b = blockIdx.x;
        size_t base = (size_t)b * C;
        int m = bcur[b * CUR_STRIDE]; if (m > C) m = C;
        const int* bp = bkt + base;
        int lane = tid & 63, wid = tid >> 6;
        for (int rep = 0; rep < REPU; ++rep) {
            sm[tid] = 0;
            __syncthreads();
            for (int i = tid; i < m; i += 512) atomicAdd(&sm[bp[i] & BMASK], 1);
            __syncthreads();
            int v = sm[tid];
            // hierarchical scan: per-wave inclusive shfl-scan, wave0 scans the 8 wave sums
            int x = v;
#pragma unroll
            for (int d = 1; d < 64; d <<= 1) {
                int t = __shfl_up(x, d);
                if (lane >= d) x += t;
            }
            if (lane == 63) wsum[wid] = x;
            __syncthreads();
            if (wid == 0) {
                int wv = (lane < 8) ? wsum[lane] : 0;
#pragma unroll
                for (int d = 1; d < 8; d <<= 1) {
                    int t = __shfl_up(wv, d);
                    if (lane >= d) wv += t;
                }
                if (lane < 8) wsum[8 + lane] = wv;   // inclusive wave prefix
            }
            __syncthreads();
            int wbase = wid ? wsum[8 + wid - 1] : 0;
            int excl = x + wbase - v;
            int node = (b << BSH) + tid;
            if (node < N) off2[node] = make_int2((int)base + excl, (int)base + excl + v);
            __syncthreads();
            sm[tid] = excl;
            __syncthreads();
            for (int i = tid; i < m; i += 512) {
                int p = bp[i];
                int r = atomicAdd(&sm[p & BMASK], 1);
                csr[base + r] = p >> BSH;
            }
            __syncthreads();
        }
    } else {
        int isf32 = *flagp;
        float ms[12], md[12];
#pragma unroll
        for (int i = 0; i < 12; ++i) { ms[i] = Mfac[i]; md[i] = Mfac[16 + i]; }
        int node = ((int)blockIdx.x - NB) * 512 + tid;
        for (int rep = 0; rep < REPU; ++rep) {
            if (node < N) {
                float x0 = cvt_elem(xr, node * 3 + 0, isf32);
                float x1 = cvt_elem(xr, node * 3 + 1, isf32);
                float x2 = cvt_elem(xr, node * 3 + 2, isf32);
                float4 as, ad;
                as.x = x0 * ms[0] + x1 * ms[4] + x2 * ms[8];
                as.y = x0 * ms[1] + x1 * ms[5] + x2 * ms[9];
                as.z = x0 * ms[2] + x1 * ms[6] + x2 * ms[10];
                as.w = x0 * ms[3] + x1 * ms[7] + x2 * ms[11];
                ad.x = x0 * md[0] + x1 * md[4] + x2 * md[8];
                ad.y = x0 * md[1] + x1 * md[5] + x2 * md[9];
                ad.z = x0 * md[2] + x1 * md[6] + x2 * md[10];
                ad.w = x0 * md[3] + x1 * md[7] + x2 * md[11];
                *(float4*)&axs[(size_t)node * 8] = as;
                *(float4*)&axs[(size_t)node * 8 + 4] = make_float4(x0, x1, x2, 0.f);
                *(float4*)&ad1[(size_t)node * 4] = ad;
            }
        }
    }
}

// ---------------- Layer 1 agg: GATConv(3, 16, heads=4) ----------------

__global__ __launch_bounds__(256) void k_l1_agg(const float* __restrict__ axs,
                                                const float4* __restrict__ ad4p, const int2* __restrict__ off2,
                                                const int* __restrict__ csr, const float* __restrict__ W1,
                                                const float* __restrict__ b1,
                                                float* __restrict__ x1, int N) {
    int tid = threadIdx.x;
    int node = blockIdx.x * 16 + (tid >> 4);
    if (node >= N) return;
    int sl = tid & 15;
    int lane = tid & 63;
    int lb = lane & 48;

    float4 ad = ad4p[node];
    int2 ee = off2[node];

    for (int rep = 0; rep < REPU; ++rep) {
        float v[16];
#pragma unroll
        for (int i = 0; i < 16; ++i) v[i] = 0.f;

        int jj = ee.x + sl;
        int sN = (jj < ee.y) ? csr[jj] : node;
        const float4* rpN = (const float4*)(axs + (size_t)sN * 8);
        float4 aN = rpN[0], xN = rpN[1];
        while (jj < ee.y) {
            float4 a = aN, xv = xN;
            int jn = jj + 16;
            int s2 = (jn < ee.y) ? csr[jn] : node;
            const float4* rp2 = (const float4*)(axs + (size_t)s2 * 8);
            aN = rp2[0]; xN = rp2[1];
            float z0 = a.x + ad.x, z1 = a.y + ad.y, z2 = a.z + ad.z, z3 = a.w + ad.w;
            z0 = (z0 > 0.f) ? z0 : 0.2f * z0;
            z1 = (z1 > 0.f) ? z1 : 0.2f * z1;
            z2 = (z2 > 0.f) ? z2 : 0.2f * z2;
            z3 = (z3 > 0.f) ? z3 : 0.2f * z3;
            float w0 = __expf(z0), w1 = __expf(z1), w2 = __expf(z2), w3 = __expf(z3);
            v[0] += w0 * xv.x; v[1] += w0 * xv.y; v[2]  += w0 * xv.z; v[3]  += w0;
            v[4] += w1 * xv.x; v[5] += w1 * xv.y; v[6]  += w1 * xv.z; v[7]  += w1;
            v[8] += w2 * xv.x; v[9] += w2 * xv.y; v[10] += w2 * xv.z; v[11] += w2;
            v[12] += w3 * xv.x; v[13] += w3 * xv.y; v[14] += w3 * xv.z; v[15] += w3;
            jj = jn;
        }

#pragma unroll
        for (int d = 8; d >= 1; d >>= 1) {
#pragma unroll
            for (int i = 0; i < 16; ++i) {
                if (i < d) {
                    float a = v[i], b = v[i + d];
                    float send = (sl & d) ? a : b;
                    float recv = __shfl_xor(send, d);
                    v[i] = ((sl & d) ? b : a) + recv;
                }
            }
        }
        float r = v[0];

        float agx[4], agy[4], agz[4], dn[4];
#pragma unroll
        for (int h = 0; h < 4; ++h) {
            agx[h] = __shfl(r, lb + 4 * h + 0);
            agy[h] = __shfl(r, lb + 4 * h + 1);
            agz[h] = __shfl(r, lb + 4 * h + 2);
            dn[h]  = __shfl(r, lb + 4 * h + 3);
        }

        {
            const float4* rp = (const float4*)(axs + (size_t)node * 8);
            float4 a = rp[0];
            float4 xv = rp[1];
            float z0 = a.x + ad.x, z1 = a.y + ad.y, z2 = a.z + ad.z, z3 = a.w + ad.w;
            z0 = (z0 > 0.f) ? z0 : 0.2f * z0;
            z1 = (z1 > 0.f) ? z1 : 0.2f * z1;
            z2 = (z2 > 0.f) ? z2 : 0.2f * z2;
            z3 = (z3 > 0.f) ? z3 : 0.2f * z3;
            float w0 = __expf(z0), w1 = __expf(z1), w2 = __expf(z2), w3 = __expf(z3);
            agx[0] += w0 * xv.x; agy[0] += w0 * xv.y; agz[0] += w0 * xv.z; dn[0] += w0;
            agx[1] += w1 * xv.x; agy[1] += w1 * xv.y; agz[1] += w1 * xv.z; dn[1] += w1;
            agx[2] += w2 * xv.x; agy[2] += w2 * xv.y; agz[2] += w2 * xv.z; dn[2] += w2;
            agx[3] += w3 * xv.x; agy[3] += w3 * xv.y; agz[3] += w3 * xv.z; dn[3] += w3;
        }

#pragma unroll
        for (int h = 0; h < 4; ++h) {
            int j = h * 16 + sl;
            float inv = 1.f / (dn[h] + 1e-16f);
            float o = (agx[h] * W1[j] + agy[h] * W1[64 + j] + agz[h] * W1[128 + j]) * inv + b1[j];
            x1[(size_t)node * 64 + j] = (o > 0.f) ? o : 0.f;
        }
    }
}

// ---------------- Layer 2: GATv2Conv(64, 16, heads=2) ----------------

__global__ __launch_bounds__(256) void k_l2_transform(const float* __restrict__ x1,
                                                      const float* __restrict__ W2l, const float* __restrict__ b2l,
                                                      const float* __restrict__ W2r, const float* __restrict__ b2r,
                                                      unsigned short* __restrict__ hlb, float* __restrict__ hr, int N) {
    __shared__ float xs[64 * 68];
    int t = threadIdx.x;
    int node0 = blockIdx.x * 64;
    int nrem = N - node0; if (nrem > 64) nrem = 64;
    const float4* xg = (const float4*)x1;
    for (int rep = 0; rep < REPU; ++rep) {
#pragma unroll
        for (int it = 0; it < 4; ++it) {
            int id = it * 256 + t;
            int row = id >> 4, c4 = id & 15;
            float4 v = make_float4(0.f, 0.f, 0.f, 0.f);
            if (row < nrem) v = xg[(size_t)(node0 + row) * 16 + c4];
            *(float4*)&xs[row * 68 + c4 * 4] = v;
        }
        __syncthreads();
        int nt = t >> 4;
        int jt = t & 15;
        int jq = jt & 7;
        int jc = jq * 4;
        const float4* W4 = (const float4*)((jt < 8) ? W2l : W2r);
        const float4* B4 = (const float4*)((jt < 8) ? b2l : b2r);
        float4 bb = B4[jq];
        float4 acc[4];
#pragma unroll
        for (int i = 0; i < 4; ++i) acc[i] = bb;
#pragma unroll 2
        for (int k4 = 0; k4 < 16; ++k4) {
            float4 w0 = W4[(k4 * 4 + 0) * 8 + jq];
            float4 w1 = W4[(k4 * 4 + 1) * 8 + jq];
            float4 w2 = W4[(k4 * 4 + 2) * 8 + jq];
            float4 w3 = W4[(k4 * 4 + 3) * 8 + jq];
#pragma unroll
            for (int i = 0; i < 4; ++i) {
                float4 xv = *(const float4*)&xs[(nt + i * 16) * 68 + k4 * 4];
                acc[i].x += xv.x * w0.x + xv.y * w1.x + xv.z * w2.x + xv.w * w3.x;
                acc[i].y += xv.x * w0.y + xv.y * w1.y + xv.z * w2.y + xv.w * w3.y;
                acc[i].z += xv.x * w0.z + xv.y * w1.z + xv.z * w2.z + xv.w * w3.z;
                acc[i].w += xv.x * w0.w + xv.y * w1.w + xv.z * w2.w + xv.w * w3.w;
            }
        }
#pragma unroll
        for (int i = 0; i < 4; ++i) {
            int row = nt + i * 16;
            if (row < nrem) {
                size_t node = node0 + row;
                if (jt < 8) {
                    uint2 p;
                    p.x = (unsigned)f2us(acc[i].x) | ((unsigned)f2us(acc[i].y) << 16);
                    p.y = (unsigned)f2us(acc[i].z) | ((unsigned)f2us(acc[i].w) << 16);
                    *(uint2*)&hlb[node * 32 + jc] = p;
                } else {
                    *(float4*)&hr[node * 32 + jc] = acc[i];
                }
            }
        }
        __syncthreads();
    }
}

// Edge-parallel, cooperative gather: 16 lanes/node = 4 edge slots x 4 channel-quarters.
// REP=1 (measured 21.7us, VALU-bound at ~87% VALUBusy).
__global__ __launch_bounds__(256) void k_l2_agg(const unsigned short* __restrict__ hlb, const float* __restrict__ hr,
                                                const float* __restrict__ att2, const float* __restrict__ b2,
                                                const int2* __restrict__ off2, const int* __restrict__ csr,
                                                float* __restrict__ x2, int N) {
    int tid = threadIdx.x;
    int node = blockIdx.x * 16 + (tid >> 4);
    if (node >= N) return;
    int sl = tid & 15;
    int g = sl & 3;
    int slot = sl >> 2;

    float hrq[8], atq[8];
    {
        const float4* h4 = (const float4*)(hr + (size_t)node * 32 + g * 8);
        float4 h0 = h4[0], h1 = h4[1];
        hrq[0] = h0.x; hrq[1] = h0.y; hrq[2] = h0.z; hrq[3] = h0.w;
        hrq[4] = h1.x; hrq[5] = h1.y; hrq[6] = h1.z; hrq[7] = h1.w;
        const float4* a4 = (const float4*)(att2 + g * 8);
        float4 a0 = a4[0], a1 = a4[1];
        atq[0] = a0.x; atq[1] = a0.y; atq[2] = a0.z; atq[3] = a0.w;
        atq[4] = a1.x; atq[5] = a1.y; atq[6] = a1.z; atq[7] = a1.w;
    }
    int2 ee = off2[node];

    float acc[8];
#pragma unroll
    for (int j = 0; j < 8; ++j) acc[j] = 0.f;
    float den = 0.f;

    int jj = ee.x + slot;
    int sN = (jj < ee.y) ? csr[jj] : node;
    uint4 uN = *(const uint4*)(hlb + (size_t)sN * 32 + g * 8);
    while (jj < ee.y) {
        uint4 u = uN;
        int jn = jj + 4;
        int s2 = (jn < ee.y) ? csr[jn] : node;
        uN = *(const uint4*)(hlb + (size_t)s2 * 32 + g * 8);
        unsigned uu[4] = {u.x, u.y, u.z, u.w};
        float hlv[8];
#pragma unroll
        for (int q = 0; q < 4; ++q) {
            hlv[2 * q]     = __uint_as_float(uu[q] << 16);
            hlv[2 * q + 1] = __uint_as_float(uu[q] & 0xFFFF0000u);
        }
        float t = 0.f;
#pragma unroll
        for (int j = 0; j < 8; ++j) {
            float e = hlv[j] + hrq[j];
            e = fmaxf(e, 0.2f * e);
            t += atq[j] * e;
        }
        t += __shfl_xor(t, 1);
        float w = __expf(t);
        den += w;
#pragma unroll
        for (int j = 0; j < 8; ++j) acc[j] += w * hlv[j];
        jj = jn;
    }

    if (slot == 0) {
        uint4 u = *(const uint4*)(hlb + (size_t)node * 32 + g * 8);
        unsigned uu[4] = {u.x, u.y, u.z, u.w};
        float hlv[8];
#pragma unroll
        for (int q = 0; q < 4; ++q) {
            hlv[2 * q]     = __uint_as_float(uu[q] << 16);
            hlv[2 * q + 1] = __uint_as_float(uu[q] & 0xFFFF0000u);
        }
        float t = 0.f;
#pragma unroll
        for (int j = 0; j < 8; ++j) {
            float e = hlv[j] + hrq[j];
            e = fmaxf(e, 0.2f * e);
            t += atq[j] * e;
        }
        t += __shfl_xor(t, 1);
        float w = __expf(t);
        den += w;
#pragma unroll
        for (int j = 0; j < 8; ++j) acc[j] += w * hlv[j];
    }

#pragma unroll
    for (int d = 4; d <= 8; d <<= 1) {
#pragma unroll
        for (int j = 0; j < 8; ++j) acc[j] += __shfl_xor(acc[j], d);
        den += __shfl_xor(den, d);
    }

    if (slot < 2) {
        float inv = 1.f / (den + 1e-16f);
        int c = g * 8 + slot * 4;
        float4 bb = *(const float4*)(b2 + c);
        float o0 = slot ? acc[4] : acc[0];
        float o1 = slot ? acc[5] : acc[1];
        float o2 = slot ? acc[6] : acc[2];
        float o3 = slot ? acc[7] : acc[3];
        *(float4*)&x2[(size_t)node * 32 + c] =
            make_float4(o0 * inv + bb.x, o1 * inv + bb.y, o2 * inv + bb.z, o3 * inv + bb.w);
    }
}

// ---------------- Layer 3: TransformerConv(32, 7, heads=1) ----------------

__global__ __launch_bounds__(256) void k_l3_transform(const float* __restrict__ x2,
                                                      const float4* __restrict__ Wc4, const float4* __restrict__ bc4,
                                                      float* __restrict__ QS, unsigned short* __restrict__ KVb, int N) {
    __shared__ float xs[128 * 36];
    int t = threadIdx.x;
    int node0 = blockIdx.x * 128;
    int nrem = N - node0; if (nrem > 128) nrem = 128;
    const float4* xg = (const float4*)x2;
    for (int rep = 0; rep < REPU; ++rep) {
#pragma unroll
        for (int it = 0; it < 4; ++it) {
            int id = it * 256 + t;
            int row = id >> 3, c4 = id & 7;
            float4 v = make_float4(0.f, 0.f, 0.f, 0.f);
            if (row < nrem) v = xg[(size_t)(node0 + row) * 8 + c4];
            *(float4*)&xs[row * 36 + c4 * 4] = v;
        }
        __syncthreads();
        int nt = t >> 3;
        int jt = t & 7;
        float4 bb = bc4[jt];
        float4 acc[4];
#pragma unroll
        for (int i = 0; i < 4; ++i) acc[i] = bb;
#pragma unroll 2
        for (int k4 = 0; k4 < 8; ++k4) {
            float4 w0 = Wc4[(k4 * 4 + 0) * 8 + jt];
            float4 w1 = Wc4[(k4 * 4 + 1) * 8 + jt];
            float4 w2 = Wc4[(k4 * 4 + 2) * 8 + jt];
            float4 w3 = Wc4[(k4 * 4 + 3) * 8 + jt];
#pragma unroll
            for (int i = 0; i < 4; ++i) {
                float4 xv = *(const float4*)&xs[(nt + i * 32) * 36 + k4 * 4];
                acc[i].x += xv.x * w0.x + xv.y * w1.x + xv.z * w2.x + xv.w * w3.x;
                acc[i].y += xv.x * w0.y + xv.y * w1.y + xv.z * w2.y + xv.w * w3.y;
                acc[i].z += xv.x * w0.z + xv.y * w1.z + xv.z * w2.z + xv.w * w3.z;
                acc[i].w += xv.x * w0.w + xv.y * w1.w + xv.z * w2.w + xv.w * w3.w;
            }
        }
#pragma unroll
        for (int i = 0; i < 4; ++i) {
            int row = nt + i * 32;
            if (row < nrem) {
                size_t node = node0 + row;
                if (jt < 4) {
                    *(float4*)(QS + node * 16 + jt * 4) = acc[i];
                } else {
                    uint2 p;
                    p.x = (unsigned)f2us(acc[i].x) | ((unsigned)f2us(acc[i].y) << 16);
                    p.y = (unsigned)f2us(acc[i].z) | ((unsigned)f2us(acc[i].w) << 16);
                    *(uint2*)&KVb[node * 16 + (size_t)(jt - 4) * 4] = p;
                }
            }
        }
        __syncthreads();
    }
}

// Edge-parallel, pair-cooperative: 16 lanes/node = 8 edge slots x 2 sides; 2-deep prefetch.
__global__ __launch_bounds__(256) void k_l3_agg(const float* __restrict__ QS, const unsigned short* __restrict__ KVb,
                                                const int2* __restrict__ off2, const int* __restrict__ csr,
                                                float* __restrict__ out, int N) {
    int tid = threadIdx.x;
    int node = blockIdx.x * 16 + (tid >> 4);
    if (node >= N) return;
    int sl = tid & 15;
    int side = sl & 1;
    int p = sl >> 1;
    int lane = tid & 63;
    const float scale = 0.3779644730092272f;  // 1/sqrt(7)
    const float4* q4 = (const float4*)(QS + (size_t)node * 16);
    float4 qa = q4[0], qb = q4[1];
    qa.x *= scale; qa.y *= scale; qa.z *= scale; qa.w *= scale;
    qb.x *= scale; qb.y *= scale; qb.z *= scale; qb.w = 0.f;
    int2 ee = off2[node];

    for (int rep = 0; rep < REPU; ++rep) {
        float v[8];
#pragma unroll
        for (int i = 0; i < 8; ++i) v[i] = 0.f;

        int jj = ee.x + p;
        int sN = (jj < ee.y) ? csr[jj] : node;
        uint4 uN = *(const uint4*)(KVb + (size_t)sN * 16 + (side << 3));
        while (jj < ee.y) {
            uint4 u = uN;
            int jn = jj + 8;
            int s2 = (jn < ee.y) ? csr[jn] : node;
            uN = *(const uint4*)(KVb + (size_t)s2 * 16 + (side << 3));
            float t = 0.f;
            if (!side) {
                float k0 = __uint_as_float(u.x << 16), k1 = __uint_as_float(u.x & 0xFFFF0000u);
                float k2 = __uint_as_float(u.y << 16), k3 = __uint_as_float(u.y & 0xFFFF0000u);
                float k4 = __uint_as_float(u.z << 16), k5 = __uint_as_float(u.z & 0xFFFF0000u);
                float k6 = __uint_as_float(u.w << 16);
                t = qa.x * k0 + qa.y * k1 + qa.z * k2 + qa.w * k3
                  + qb.x * k4 + qb.y * k5 + qb.z * k6;
            }
            float tf = __shfl_xor(t, 1);
            if (side) {
                float w = __expf(tf);
                v[0] += w * __uint_as_float(u.x << 16);
                v[1] += w * __uint_as_float(u.x & 0xFFFF0000u);
                v[2] += w * __uint_as_float(u.y << 16);
                v[3] += w * __uint_as_float(u.y & 0xFFFF0000u);
                v[4] += w * __uint_as_float(u.z << 16);
                v[5] += w * __uint_as_float(u.z & 0xFFFF0000u);
                v[6] += w * __uint_as_float(u.w << 16);
                v[7] += w;
            }
            jj = jn;
        }

#pragma unroll
        for (int d = 4; d >= 1; d >>= 1) {
#pragma unroll
            for (int i = 0; i < 8; ++i) {
                if (i < d) {
                    float a = v[i], b = v[i + d];
                    float send = (p & d) ? a : b;
                    float recv = __shfl_xor(send, d << 1);
                    v[i] = ((p & d) ? b : a) + recv;
                }
            }
        }
        float r = v[0];
        float den = __shfl(r, (lane & 48) | 15);
        if (side && p < 7) out[(size_t)node * 7 + p] = r / (den + 1e-16f)
                                                       + QS[(size_t)node * 16 + 8 + p];
    }
}

// ---------------- launcher ----------------

extern "C" void kernel_launch(void* const* d_in, const int* in_sizes, int n_in,
                              void* d_out, int out_size, void* d_ws, size_t ws_size,
                              hipStream_t stream) {
    const int* ei = (const int*)d_in[1];
    float* out = (float*)d_out;

    int N = in_sizes[0] / 3;
    int E = in_sizes[1] / 2;
    int NB = (N + BMASK) >> BSH;        // assumed <= 512 (N <= 262144)
    int C = (E + NB - 1) / NB + 4096;

    char* ws = (char*)d_ws;
    size_t o = 0;
    auto take = [&](size_t bytes) -> char* {
        char* p = ws + o;
        o = (o + bytes + 255) & ~(size_t)255;
        return p;
    };
    int total_f = 0;
    for (int i = 2; i < 20; ++i) total_f += in_sizes[i];
    float* canon   = (float*)take((size_t)total_f * 4);
    float* Wcat    = (float*)take(32 * 32 * 4);
    float* bcat    = (float*)take(32 * 4);
    float* Mfac    = (float*)take(32 * 4);
    int2*  off2    = (int2*)take((size_t)N * 8);
    int*   bcur    = (int*)take((512 * CUR_STRIDE + 1) * 4);
    int*   csr     = (int*)take((size_t)NB * C * 4);
    float* bufA    = (float*)take((size_t)N * 64 * 4);  // axs -> hlb|hr -> QS|KVb
    float* ad1     = (float*)take((size_t)N * 4 * 4);
    float* bufB    = (float*)take((size_t)N * 64 * 4);  // bkt -> x1 -> x2
    (void)ws_size; (void)n_in; (void)out_size;

    CvtArgs ca;
    const float* cp[20];
    {
        int off_ = 0, k = 0;
        for (int i = 0; i < 20; ++i) {
            if (i < 2) { cp[i] = nullptr; continue; }
            ca.p[k] = d_in[i];
            ca.sz[k] = in_sizes[i];
            cp[i] = canon + off_;
            off_ += in_sizes[i];
            ++k;
        }
    }

    int nbconv = (total_f + 255) / 256;
    k_convert<<<nbconv + 1, 256, 0, stream>>>(ca, (const unsigned short*)d_in[0], canon, total_f,
                                              nbconv, Wcat, bcat, Mfac, bcur);
    const int* flagp = bcur + 512 * CUR_STRIDE;

    int* bkt = (int*)bufB;
    int gb = (E + 4095) / 4096;
    k_bscatter<<<gb, 1024, 0, stream>>>(ei, bcur, bkt, E, NB, C);

    float* axs = bufA;
    int nbl1 = (N + 511) >> 9;
    k_bbuild_l1t<<<NB + nbl1, 512, 0, stream>>>(bkt, bcur, off2, csr, d_in[0], flagp, Mfac,
                                                axs, ad1, N, NB, C);

    float* x1 = bufB;
    k_l1_agg<<<(N + 15) / 16, 256, 0, stream>>>(axs, (const float4*)ad1, off2, csr, cp[2], cp[5], x1, N);

    unsigned short* hlb = (unsigned short*)bufA;
    float* hr = bufA + (size_t)N * 16;
    k_l2_transform<<<(N + 63) / 64, 256, 0, stream>>>(x1, cp[6], cp[7], cp[8], cp[9], hlb, hr, N);
    float* x2 = bufB;
    k_l2_agg<<<(N + 15) / 16, 256, 0, stream>>>(hlb, hr, cp[10], cp[11], off2, csr, x2, N);

    float* QS = bufA;
    unsigned short* KVb = (unsigned short*)(bufA + (size_t)N * 16);
    k_l3_transform<<<(N + 127) / 128, 256, 0, stream>>>(x2, (const float4*)Wcat, (const float4*)bcat,
                                                        QS, KVb, N);
    k_l3_agg<<<(N + 15) / 16, 256, 0, stream>>>(QS, KVb, off2, csr, out, N);
}

// Round 4
// 229.422 us; speedup vs baseline: 3.0861x; 2.4970x over previous
//
#include <hip/hip_runtime.h>
#include <hip/hip_bf16.h>

typedef __hip_bfloat16 bf16;
typedef __attribute__((ext_vector_type(8))) short bf16x8;   // 8 bf16 (4 VGPRs) MFMA A/B frag
typedef __attribute__((ext_vector_type(4))) float f32x4;    // MFMA C/D frag

static __device__ __forceinline__ float us2f(unsigned short u) {
    union { unsigned int i; float f; } c; c.i = ((unsigned int)u) << 16; return c.f;
}
static __device__ __forceinline__ unsigned short f2us(float f) {
    union { float f; unsigned int i; } c; c.f = f;
    unsigned int r = c.i + 0x7FFF + ((c.i >> 16) & 1);   // round-to-nearest-even
    return (unsigned short)(r >> 16);
}

// wave-0 probe: is the float input stored as f32 (vs bf16)?
static __device__ __forceinline__ int probe_isf32(const unsigned short* xr, int* sflag) {
    int tid = threadIdx.x;
    if (tid < 64) {
        int bad = 0;
        for (int i = tid; i < 1024; i += 64) {
            int ex = (xr[2 * i] >> 7) & 0xFF;
            if (ex < 110 || ex > 135) bad++;
        }
#pragma unroll
        for (int m = 32; m >= 1; m >>= 1) bad += __shfl_xor(bad, m);
        if (tid == 0) *sflag = (bad > 256) ? 1 : 0;
    }
    __syncthreads();
    return *sflag;
}

static __device__ __forceinline__ int ld_edge(const int* er, size_t i, int idx64) {
    return idx64 ? er[2 * i] : er[i];
}

#define BSH 9
#define BMASK 511
#define CUR_STRIDE 16   // bucket cursors padded to 64B: no same-line atomic serialization

// ---------------- canonicalization + W-frag pack + bcur zero (fused) ----------------

struct CvtArgs { const void* p[18]; int sz[18]; };

static __device__ __forceinline__ float cvt_elem(const void* p, int off, int isf32) {
    return isf32 ? ((const float*)p)[off] : __bfloat162float(((const bf16*)p)[off]);
}

// blocks 0..nbconv-1: convert weight inputs to f32 canon.
// block nbconv: MFMA W-fragment packs (hi/lo split), bcat, bias64, Mfac, bcur zero, flag.
__global__ __launch_bounds__(256) void k_convert(CvtArgs a, const unsigned short* __restrict__ xraw,
                                                 float* __restrict__ dst, int total, int nbconv,
                                                 unsigned short* __restrict__ Wp2h, unsigned short* __restrict__ Wp2l,
                                                 unsigned short* __restrict__ Wp3h, unsigned short* __restrict__ Wp3l,
                                                 float* __restrict__ bias64,
                                                 float* __restrict__ bcat, float* __restrict__ Mfac,
                                                 int* __restrict__ bcur) {
    __shared__ int sflag;
    int isf32 = probe_isf32(xraw, &sflag);
    int tid = threadIdx.x;
    if ((int)blockIdx.x == nbconv) {
        // p-map: 0=W1 1=att_src1 2=att_dst1 3=b1 4=W2l 5=b2l 6=W2r 7=b2r 8=att2 9=b2
        //        10=Wq 11=bq 12=Wk 13=bk 14=Wv 15=bv 16=Wskip 17=bskip
        // Wp2 fragments: lane-ordered A/B frags for l2 MFMA. f = ((t4*2+s)*64+lane)*8+i
#pragma unroll
        for (int rr = 0; rr < 16; ++rr) {
            int f = rr * 256 + tid;             // 0..4095
            int i = f & 7, lane = (f >> 3) & 63, s = (f >> 9) & 1, t4 = f >> 10;
            int k = 32 * s + ((lane >> 4) << 3) + i;
            int c = 16 * t4 + (lane & 15);
            float w = (c < 32) ? cvt_elem(a.p[4], k * 32 + c, isf32)
                               : cvt_elem(a.p[6], k * 32 + (c - 32), isf32);
            unsigned short hb = f2us(w);
            Wp2h[f] = hb;
            Wp2l[f] = f2us(w - us2f(hb));
        }
        // Wp3 fragments: combined [Wq|Wskip|Wk|Wv] (each 7 cols + zero pad to 8)
#pragma unroll
        for (int rr = 0; rr < 4; ++rr) {
            int f = rr * 256 + tid;             // 0..1023
            int i = f & 7, lane = (f >> 3) & 63, t3 = f >> 9;
            int k = ((lane >> 4) << 3) + i;
            int c = 16 * t3 + (lane & 15);
            int g = c >> 3, cc = c & 7;
            const void* Wg = (g == 0) ? a.p[10] : (g == 1) ? a.p[16] : (g == 2) ? a.p[12] : a.p[14];
            float w = (cc < 7) ? cvt_elem(Wg, k * 7 + cc, isf32) : 0.f;
            unsigned short hb = f2us(w);
            Wp3h[f] = hb;
            Wp3l[f] = f2us(w - us2f(hb));
        }
        if (tid < 64) bias64[tid] = (tid < 32) ? cvt_elem(a.p[5], tid, isf32)
                                               : cvt_elem(a.p[7], tid - 32, isf32);
        if (tid < 32) {
            int g = tid >> 3, cc = tid & 7;
            const void* Bg = (g == 0) ? a.p[11] : (g == 1) ? a.p[17] : (g == 2) ? a.p[13] : a.p[15];
            bcat[tid] = (cc < 7) ? cvt_elem(Bg, cc, isf32) : 0.f;
        }
        // Mfac: Ms[k][H] = sum_c W1[k][16H+c]*att_src1[H][c]; Md with att_dst1.
        if (tid < 24) {
            int which = tid / 12;
            int r = tid % 12; int k = r >> 2, H = r & 3;
            const void* W1p = a.p[0];
            const void* ap = which ? a.p[2] : a.p[1];
            float s = 0.f;
            for (int c = 0; c < 16; ++c)
                s += cvt_elem(W1p, k * 64 + H * 16 + c, isf32) * cvt_elem(ap, H * 16 + c, isf32);
            Mfac[which * 16 + k * 4 + H] = s;
        }
        for (int i = tid; i < 512 * CUR_STRIDE + 1; i += 256) bcur[i] = 0;
        __syncthreads();
        if (tid == 0) bcur[512 * CUR_STRIDE] = isf32;
        return;
    }
    int t = blockIdx.x * 256 + tid;
    if (t >= total) return;
    int base = 0, seg = -1, off = 0;
#pragma unroll
    for (int i = 0; i < 18; i++) {
        if (seg < 0 && t < base + a.sz[i]) { seg = i; off = t - base; }
        base += a.sz[i];
    }
    dst[t] = cvt_elem(a.p[seg], off, isf32);
}

// ---------------- bucketed CSR build (512-node buckets; packed bkt) ----------------

__global__ __launch_bounds__(1024) void k_bscatter(const int* __restrict__ er,
                                                   int* __restrict__ bcur, int* __restrict__ bkt,
                                                   int E, int NB, int C) {
    __shared__ int cnt[512];
    __shared__ int res[512];
    __shared__ int sflag;
    int tid = threadIdx.x;
    if (tid < 64) {
        int lim = (E < 1024) ? E : 1024;
        int nz = 0;
        for (int i = tid; i < lim; i += 64) if (er[2 * i + 1] != 0) nz++;
#pragma unroll
        for (int m = 32; m >= 1; m >>= 1) nz += __shfl_xor(nz, m);
        if (tid == 0) sflag = (nz < ((E < 1024 ? E : 1024) >> 1)) ? 1 : 0;
    }
    if (tid < 512) cnt[tid] = 0;
    __syncthreads();
    int idx64 = sflag;
    int e0 = blockIdx.x * 4096 + tid * 4;
    int sv[4], dv[4];
    bool val[4];
    bool fast = (e0 + 4 <= E) && ((E & 3) == 0);
    if (fast) {
        const int4* p4 = (const int4*)er;
        if (idx64) {
            int4 u0 = p4[e0 >> 1], u1 = p4[(e0 >> 1) + 1];
            int4 w0 = p4[(E + e0) >> 1], w1 = p4[((E + e0) >> 1) + 1];
            sv[0] = u0.x; sv[1] = u0.z; sv[2] = u1.x; sv[3] = u1.z;
            dv[0] = w0.x; dv[1] = w0.z; dv[2] = w1.x; dv[3] = w1.z;
        } else {
            int4 u = p4[e0 >> 2];
            int4 w = p4[(E + e0) >> 2];
            sv[0] = u.x; sv[1] = u.y; sv[2] = u.z; sv[3] = u.w;
            dv[0] = w.x; dv[1] = w.y; dv[2] = w.z; dv[3] = w.w;
        }
#pragma unroll
        for (int k = 0; k < 4; ++k) val[k] = true;
    } else {
#pragma unroll
        for (int k = 0; k < 4; ++k) {
            int e = e0 + k;
            val[k] = (e < E);
            if (val[k]) {
                sv[k] = ld_edge(er, (size_t)e, idx64);
                dv[k] = ld_edge(er, (size_t)E + e, idx64);
            }
        }
    }
    int pk[4], bv[4];
#pragma unroll
    for (int k = 0; k < 4; ++k) {
        if (val[k]) {
            bv[k] = dv[k] >> BSH;
            pk[k] = (sv[k] << BSH) | (dv[k] & BMASK);
            atomicAdd(&cnt[bv[k]], 1);
        }
    }
    __syncthreads();
    if (tid < NB) {
        int c = cnt[tid];
        res[tid] = c ? atomicAdd(&bcur[tid * CUR_STRIDE], c) : 0;
        cnt[tid] = 0;
    }
    __syncthreads();
#pragma unroll
    for (int k = 0; k < 4; ++k) {
        if (val[k]) {
            int r = res[bv[k]] + atomicAdd(&cnt[bv[k]], 1);
            if (r < C) bkt[(size_t)bv[k] * C + r] = pk[k];
        }
    }
}

// blocks < NB: per-bucket indeg count + hierarchical wave-scan -> off2; scatter src -> csr.
// blocks >= NB: layer-1 transform (M-factored): axs = {x.Ms, x, 0}, ad1 = x.Md.
__global__ __launch_bounds__(512) void k_bbuild_l1t(const int* __restrict__ bkt, const int* __restrict__ bcur,
                                                    int2* __restrict__ off2, int* __restrict__ csr,
                                                    const void* __restrict__ xr, const int* __restrict__ flagp,
                                                    const float* __restrict__ Mfac,
                                                    float* __restrict__ axs, float* __restrict__ ad1,
                                                    int N, int NB, int C) {
    int tid = threadIdx.x;
    if ((int)blockIdx.x < NB) {
        __shared__ int sm[512];
        __shared__ int wsum[16];
        int b = blockIdx.x;
        size_t base = (size_t)b * C;
        int m = bcur[b * CUR_STRIDE]; if (m > C) m = C;
        const int* bp = bkt + base;
        int lane = tid & 63, wid = tid >> 6;
        sm[tid] = 0;
        __syncthreads();
        for (int i = tid; i < m; i += 512) atomicAdd(&sm[bp[i] & BMASK], 1);
        __syncthreads();
        int v = sm[tid];
        // hierarchical scan: per-wave inclusive shfl-scan; wave0 scans the 8 wave sums
        int x = v;
#pragma unroll
        for (int d = 1; d < 64; d <<= 1) {
            int t = __shfl_up(x, d);
            if (lane >= d) x += t;
        }
        if (lane == 63) wsum[wid] = x;
        __syncthreads();
        if (wid == 0) {
            int wv = (lane < 8) ? wsum[lane] : 0;
#pragma unroll
            for (int d = 1; d < 8; d <<= 1) {
                int t = __shfl_up(wv, d);
                if (lane >= d) wv += t;
            }
            if (lane < 8) wsum[8 + lane] = wv;
        }
        __syncthreads();
        int wbase = wid ? wsum[8 + wid - 1] : 0;
        int excl = x + wbase - v;
        int node = (b << BSH) + tid;
        if (node < N) off2[node] = make_int2((int)base + excl, (int)base + excl + v);
        __syncthreads();
        sm[tid] = excl;
        __syncthreads();
        for (int i = tid; i < m; i += 512) {
            int p = bp[i];
            int r = atomicAdd(&sm[p & BMASK], 1);
            csr[base + r] = p >> BSH;
        }
    } else {
        int isf32 = *flagp;
        float ms[12], md[12];
#pragma unroll
        for (int i = 0; i < 12; ++i) { ms[i] = Mfac[i]; md[i] = Mfac[16 + i]; }
        int node = ((int)blockIdx.x - NB) * 512 + tid;
        if (node < N) {
            float x0 = cvt_elem(xr, node * 3 + 0, isf32);
            float x1 = cvt_elem(xr, node * 3 + 1, isf32);
            float x2 = cvt_elem(xr, node * 3 + 2, isf32);
            float4 as, ad;
            as.x = x0 * ms[0] + x1 * ms[4] + x2 * ms[8];
            as.y = x0 * ms[1] + x1 * ms[5] + x2 * ms[9];
            as.z = x0 * ms[2] + x1 * ms[6] + x2 * ms[10];
            as.w = x0 * ms[3] + x1 * ms[7] + x2 * ms[11];
            ad.x = x0 * md[0] + x1 * md[4] + x2 * md[8];
            ad.y = x0 * md[1] + x1 * md[5] + x2 * md[9];
            ad.z = x0 * md[2] + x1 * md[6] + x2 * md[10];
            ad.w = x0 * md[3] + x1 * md[7] + x2 * md[11];
            *(float4*)&axs[(size_t)node * 8] = as;
            *(float4*)&axs[(size_t)node * 8 + 4] = make_float4(x0, x1, x2, 0.f);
            *(float4*)&ad1[(size_t)node * 4] = ad;
        }
    }
}

// ---------------- Layer 1 agg: GATConv(3, 16, heads=4) ----------------

__global__ __launch_bounds__(256) void k_l1_agg(const float* __restrict__ axs,
                                                const float4* __restrict__ ad4p, const int2* __restrict__ off2,
                                                const int* __restrict__ csr, const float* __restrict__ W1,
                                                const float* __restrict__ b1,
                                                float* __restrict__ x1, int N) {
    int tid = threadIdx.x;
    int node = blockIdx.x * 16 + (tid >> 4);
    if (node >= N) return;
    int sl = tid & 15;
    int lane = tid & 63;
    int lb = lane & 48;

    float4 ad = ad4p[node];
    int2 ee = off2[node];

    float v[16];
#pragma unroll
    for (int i = 0; i < 16; ++i) v[i] = 0.f;

    int jj = ee.x + sl;
    int sN = (jj < ee.y) ? csr[jj] : node;
    const float4* rpN = (const float4*)(axs + (size_t)sN * 8);
    float4 aN = rpN[0], xN = rpN[1];
    while (jj < ee.y) {
        float4 a = aN, xv = xN;
        int jn = jj + 16;
        int s2 = (jn < ee.y) ? csr[jn] : node;
        const float4* rp2 = (const float4*)(axs + (size_t)s2 * 8);
        aN = rp2[0]; xN = rp2[1];
        float z0 = a.x + ad.x, z1 = a.y + ad.y, z2 = a.z + ad.z, z3 = a.w + ad.w;
        z0 = (z0 > 0.f) ? z0 : 0.2f * z0;
        z1 = (z1 > 0.f) ? z1 : 0.2f * z1;
        z2 = (z2 > 0.f) ? z2 : 0.2f * z2;
        z3 = (z3 > 0.f) ? z3 : 0.2f * z3;
        float w0 = __expf(z0), w1 = __expf(z1), w2 = __expf(z2), w3 = __expf(z3);
        v[0] += w0 * xv.x; v[1] += w0 * xv.y; v[2]  += w0 * xv.z; v[3]  += w0;
        v[4] += w1 * xv.x; v[5] += w1 * xv.y; v[6]  += w1 * xv.z; v[7]  += w1;
        v[8] += w2 * xv.x; v[9] += w2 * xv.y; v[10] += w2 * xv.z; v[11] += w2;
        v[12] += w3 * xv.x; v[13] += w3 * xv.y; v[14] += w3 * xv.z; v[15] += w3;
        jj = jn;
    }

#pragma unroll
    for (int d = 8; d >= 1; d >>= 1) {
#pragma unroll
        for (int i = 0; i < 16; ++i) {
            if (i < d) {
                float a = v[i], b = v[i + d];
                float send = (sl & d) ? a : b;
                float recv = __shfl_xor(send, d);
                v[i] = ((sl & d) ? b : a) + recv;
            }
        }
    }
    float r = v[0];

    float agx[4], agy[4], agz[4], dn[4];
#pragma unroll
    for (int h = 0; h < 4; ++h) {
        agx[h] = __shfl(r, lb + 4 * h + 0);
        agy[h] = __shfl(r, lb + 4 * h + 1);
        agz[h] = __shfl(r, lb + 4 * h + 2);
        dn[h]  = __shfl(r, lb + 4 * h + 3);
    }

    {
        const float4* rp = (const float4*)(axs + (size_t)node * 8);
        float4 a = rp[0];
        float4 xv = rp[1];
        float z0 = a.x + ad.x, z1 = a.y + ad.y, z2 = a.z + ad.z, z3 = a.w + ad.w;
        z0 = (z0 > 0.f) ? z0 : 0.2f * z0;
        z1 = (z1 > 0.f) ? z1 : 0.2f * z1;
        z2 = (z2 > 0.f) ? z2 : 0.2f * z2;
        z3 = (z3 > 0.f) ? z3 : 0.2f * z3;
        float w0 = __expf(z0), w1 = __expf(z1), w2 = __expf(z2), w3 = __expf(z3);
        agx[0] += w0 * xv.x; agy[0] += w0 * xv.y; agz[0] += w0 * xv.z; dn[0] += w0;
        agx[1] += w1 * xv.x; agy[1] += w1 * xv.y; agz[1] += w1 * xv.z; dn[1] += w1;
        agx[2] += w2 * xv.x; agy[2] += w2 * xv.y; agz[2] += w2 * xv.z; dn[2] += w2;
        agx[3] += w3 * xv.x; agy[3] += w3 * xv.y; agz[3] += w3 * xv.z; dn[3] += w3;
    }

#pragma unroll
    for (int h = 0; h < 4; ++h) {
        int j = h * 16 + sl;
        float inv = 1.f / (dn[h] + 1e-16f);
        float o = (agx[h] * W1[j] + agy[h] * W1[64 + j] + agz[h] * W1[128 + j]) * inv + b1[j];
        x1[(size_t)node * 64 + j] = (o > 0.f) ? o : 0.f;
    }
}

// ---------------- Layer 2 transform: MFMA split-precision GEMM [N,64]x[64,64] ----------------
// 64 nodes/block (4 waves x 16-node M-tiles). hl = cols 0-31 (bf16 out), hr = cols 32-63 (f32 out).
// Split precision: x = xh + xl (bf16 pair), W = Wh + Wl; C = Xh.Wh + Xl.Wh + Xh.Wl (xl.wl ~ 2^-18, dropped).

__global__ __launch_bounds__(256) void k_l2_transform(const float* __restrict__ x1,
                                                      const unsigned short* __restrict__ Wp2h,
                                                      const unsigned short* __restrict__ Wp2l,
                                                      const float* __restrict__ bias64,
                                                      unsigned short* __restrict__ hlb, float* __restrict__ hr, int N) {
    __shared__ float xs[64 * 68];
    int t = threadIdx.x;
    int node0 = blockIdx.x * 64;
    int nrem = N - node0; if (nrem > 64) nrem = 64;
    const float4* xg = (const float4*)x1;
#pragma unroll
    for (int it = 0; it < 4; ++it) {
        int id = it * 256 + t;
        int row = id >> 4, c4 = id & 15;
        float4 v = make_float4(0.f, 0.f, 0.f, 0.f);
        if (row < nrem) v = xg[(size_t)(node0 + row) * 16 + c4];
        *(float4*)&xs[row * 68 + c4 * 4] = v;
    }
    __syncthreads();

    int w = t >> 6, lane = t & 63;
    int rowl = 16 * w + (lane & 15);
    int koff = (lane >> 4) * 8;

    // A fragments (hi/lo) for both K-steps
    bf16x8 xh[2], xl[2];
#pragma unroll
    for (int s = 0; s < 2; ++s) {
#pragma unroll
        for (int i = 0; i < 8; ++i) {
            float v = xs[rowl * 68 + 32 * s + koff + i];
            unsigned short hb = f2us(v);
            xh[s][i] = (short)hb;
            xl[s][i] = (short)f2us(v - us2f(hb));
        }
    }

    const bf16x8* Wh = (const bf16x8*)Wp2h;
    const bf16x8* Wl = (const bf16x8*)Wp2l;
    f32x4 acc[4];
#pragma unroll
    for (int t4 = 0; t4 < 4; ++t4) {
        f32x4 a = {0.f, 0.f, 0.f, 0.f};
#pragma unroll
        for (int s = 0; s < 2; ++s) {
            bf16x8 wh = Wh[(t4 * 2 + s) * 64 + lane];
            bf16x8 wl = Wl[(t4 * 2 + s) * 64 + lane];
            a = __builtin_amdgcn_mfma_f32_16x16x32_bf16(xh[s], wh, a, 0, 0, 0);
            a = __builtin_amdgcn_mfma_f32_16x16x32_bf16(xl[s], wh, a, 0, 0, 0);
            a = __builtin_amdgcn_mfma_f32_16x16x32_bf16(xh[s], wl, a, 0, 0, 0);
        }
        acc[t4] = a;
    }

    __syncthreads();
    // C scatter to LDS: col = lane&15 (+16*t4), row = (lane>>4)*4 + reg (+16*w); + bias
#pragma unroll
    for (int t4 = 0; t4 < 4; ++t4) {
        float bb = bias64[16 * t4 + (lane & 15)];
        int col = 16 * t4 + (lane & 15);
#pragma unroll
        for (int r = 0; r < 4; ++r) {
            int rowm = 16 * w + (lane >> 4) * 4 + r;
            xs[rowm * 68 + col] = acc[t4][r] + bb;
        }
    }
    __syncthreads();

    // write-out: thread -> (node, 8-col group q): hl cols 0-31 bf16-packed, hr cols 32-63 f32
    int node = t >> 2, q = t & 3;
    if (node < nrem) {
        size_t gn = node0 + node;
        const float* row = &xs[node * 68];
        {
            float v0 = row[8 * q + 0], v1 = row[8 * q + 1], v2 = row[8 * q + 2], v3 = row[8 * q + 3];
            float v4 = row[8 * q + 4], v5 = row[8 * q + 5], v6 = row[8 * q + 6], v7 = row[8 * q + 7];
            uint4 pk;
            pk.x = (unsigned)f2us(v0) | ((unsigned)f2us(v1) << 16);
            pk.y = (unsigned)f2us(v2) | ((unsigned)f2us(v3) << 16);
            pk.z = (unsigned)f2us(v4) | ((unsigned)f2us(v5) << 16);
            pk.w = (unsigned)f2us(v6) | ((unsigned)f2us(v7) << 16);
            *(uint4*)&hlb[gn * 32 + 8 * q] = pk;
        }
        {
            float4 h0 = *(const float4*)&row[32 + 8 * q];
            float4 h1 = *(const float4*)&row[32 + 8 * q + 4];
            *(float4*)&hr[gn * 32 + 8 * q] = h0;
            *(float4*)&hr[gn * 32 + 8 * q + 4] = h1;
        }
    }
}

// Edge-parallel, cooperative gather: 16 lanes/node = 4 edge slots x 4 channel-quarters.
__global__ __launch_bounds__(256) void k_l2_agg(const unsigned short* __restrict__ hlb, const float* __restrict__ hr,
                                                const float* __restrict__ att2, const float* __restrict__ b2,
                                                const int2* __restrict__ off2, const int* __restrict__ csr,
                                                float* __restrict__ x2, int N) {
    int tid = threadIdx.x;
    int node = blockIdx.x * 16 + (tid >> 4);
    if (node >= N) return;
    int sl = tid & 15;
    int g = sl & 3;
    int slot = sl >> 2;

    float hrq[8], atq[8];
    {
        const float4* h4 = (const float4*)(hr + (size_t)node * 32 + g * 8);
        float4 h0 = h4[0], h1 = h4[1];
        hrq[0] = h0.x; hrq[1] = h0.y; hrq[2] = h0.z; hrq[3] = h0.w;
        hrq[4] = h1.x; hrq[5] = h1.y; hrq[6] = h1.z; hrq[7] = h1.w;
        const float4* a4 = (const float4*)(att2 + g * 8);
        float4 a0 = a4[0], a1 = a4[1];
        atq[0] = a0.x; atq[1] = a0.y; atq[2] = a0.z; atq[3] = a0.w;
        atq[4] = a1.x; atq[5] = a1.y; atq[6] = a1.z; atq[7] = a1.w;
    }
    int2 ee = off2[node];

    float acc[8];
#pragma unroll
    for (int j = 0; j < 8; ++j) acc[j] = 0.f;
    float den = 0.f;

    int jj = ee.x + slot;
    int sN = (jj < ee.y) ? csr[jj] : node;
    uint4 uN = *(const uint4*)(hlb + (size_t)sN * 32 + g * 8);
    while (jj < ee.y) {
        uint4 u = uN;
        int jn = jj + 4;
        int s2 = (jn < ee.y) ? csr[jn] : node;
        uN = *(const uint4*)(hlb + (size_t)s2 * 32 + g * 8);
        unsigned uu[4] = {u.x, u.y, u.z, u.w};
        float hlv[8];
#pragma unroll
        for (int q = 0; q < 4; ++q) {
            hlv[2 * q]     = __uint_as_float(uu[q] << 16);
            hlv[2 * q + 1] = __uint_as_float(uu[q] & 0xFFFF0000u);
        }
        float t = 0.f;
#pragma unroll
        for (int j = 0; j < 8; ++j) {
            float e = hlv[j] + hrq[j];
            e = fmaxf(e, 0.2f * e);
            t += atq[j] * e;
        }
        t += __shfl_xor(t, 1);
        float w = __expf(t);
        den += w;
#pragma unroll
        for (int j = 0; j < 8; ++j) acc[j] += w * hlv[j];
        jj = jn;
    }

    if (slot == 0) {
        uint4 u = *(const uint4*)(hlb + (size_t)node * 32 + g * 8);
        unsigned uu[4] = {u.x, u.y, u.z, u.w};
        float hlv[8];
#pragma unroll
        for (int q = 0; q < 4; ++q) {
            hlv[2 * q]     = __uint_as_float(uu[q] << 16);
            hlv[2 * q + 1] = __uint_as_float(uu[q] & 0xFFFF0000u);
        }
        float t = 0.f;
#pragma unroll
        for (int j = 0; j < 8; ++j) {
            float e = hlv[j] + hrq[j];
            e = fmaxf(e, 0.2f * e);
            t += atq[j] * e;
        }
        t += __shfl_xor(t, 1);
        float w = __expf(t);
        den += w;
#pragma unroll
        for (int j = 0; j < 8; ++j) acc[j] += w * hlv[j];
    }

#pragma unroll
    for (int d = 4; d <= 8; d <<= 1) {
#pragma unroll
        for (int j = 0; j < 8; ++j) acc[j] += __shfl_xor(acc[j], d);
        den += __shfl_xor(den, d);
    }

    if (slot < 2) {
        float inv = 1.f / (den + 1e-16f);
        int c = g * 8 + slot * 4;
        float4 bb = *(const float4*)(b2 + c);
        float o0 = slot ? acc[4] : acc[0];
        float o1 = slot ? acc[5] : acc[1];
        float o2 = slot ? acc[6] : acc[2];
        float o3 = slot ? acc[7] : acc[3];
        *(float4*)&x2[(size_t)node * 32 + c] =
            make_float4(o0 * inv + bb.x, o1 * inv + bb.y, o2 * inv + bb.z, o3 * inv + bb.w);
    }
}

// ---------------- Layer 3 transform: MFMA split-precision GEMM [N,32]x[32,32] ----------------
// 64 nodes/block. Cols 0-15 -> QS (f32: Q 0-6, skip 8-15 region per Wcat grouping); 16-31 -> KVb bf16.

__global__ __launch_bounds__(256) void k_l3_transform(const float* __restrict__ x2,
                                                      const unsigned short* __restrict__ Wp3h,
                                                      const unsigned short* __restrict__ Wp3l,
                                                      const float* __restrict__ bcat,
                                                      float* __restrict__ QS, unsigned short* __restrict__ KVb, int N) {
    __shared__ float xs[64 * 36];
    int t = threadIdx.x;
    int node0 = blockIdx.x * 64;
    int nrem = N - node0; if (nrem > 64) nrem = 64;
    const float4* xg = (const float4*)x2;
#pragma unroll
    for (int it = 0; it < 2; ++it) {
        int id = it * 256 + t;
        int row = id >> 3, c4 = id & 7;
        float4 v = make_float4(0.f, 0.f, 0.f, 0.f);
        if (row < nrem) v = xg[(size_t)(node0 + row) * 8 + c4];
        *(float4*)&xs[row * 36 + c4 * 4] = v;
    }
    __syncthreads();

    int w = t >> 6, lane = t & 63;
    int rowl = 16 * w + (lane & 15);
    int koff = (lane >> 4) * 8;

    bf16x8 xh, xl;
#pragma unroll
    for (int i = 0; i < 8; ++i) {
        float v = xs[rowl * 36 + koff + i];
        unsigned short hb = f2us(v);
        xh[i] = (short)hb;
        xl[i] = (short)f2us(v - us2f(hb));
    }

    const bf16x8* Wh = (const bf16x8*)Wp3h;
    const bf16x8* Wl = (const bf16x8*)Wp3l;
    f32x4 acc[2];
#pragma unroll
    for (int t3 = 0; t3 < 2; ++t3) {
        f32x4 a = {0.f, 0.f, 0.f, 0.f};
        bf16x8 wh = Wh[t3 * 64 + lane];
        bf16x8 wl = Wl[t3 * 64 + lane];
        a = __builtin_amdgcn_mfma_f32_16x16x32_bf16(xh, wh, a, 0, 0, 0);
        a = __builtin_amdgcn_mfma_f32_16x16x32_bf16(xl, wh, a, 0, 0, 0);
        a = __builtin_amdgcn_mfma_f32_16x16x32_bf16(xh, wl, a, 0, 0, 0);
        acc[t3] = a;
    }

    __syncthreads();
#pragma unroll
    for (int t3 = 0; t3 < 2; ++t3) {
        float bb = bcat[16 * t3 + (lane & 15)];
        int col = 16 * t3 + (lane & 15);
#pragma unroll
        for (int r = 0; r < 4; ++r) {
            int rowm = 16 * w + (lane >> 4) * 4 + r;
            xs[rowm * 36 + col] = acc[t3][r] + bb;
        }
    }
    __syncthreads();

    int node = t >> 2, q = t & 3;
    if (node < nrem) {
        size_t gn = node0 + node;
        const float* row = &xs[node * 36];
        if (q < 2) {
            float4 h0 = *(const float4*)&row[8 * q];
            float4 h1 = *(const float4*)&row[8 * q + 4];
            *(float4*)(QS + gn * 16 + 8 * q) = h0;
            *(float4*)(QS + gn * 16 + 8 * q + 4) = h1;
        } else {
            int qq = q - 2;
            float v0 = row[16 + 8 * qq + 0], v1 = row[16 + 8 * qq + 1];
            float v2 = row[16 + 8 * qq + 2], v3 = row[16 + 8 * qq + 3];
            float v4 = row[16 + 8 * qq + 4], v5 = row[16 + 8 * qq + 5];
            float v6 = row[16 + 8 * qq + 6], v7 = row[16 + 8 * qq + 7];
            uint4 pk;
            pk.x = (unsigned)f2us(v0) | ((unsigned)f2us(v1) << 16);
            pk.y = (unsigned)f2us(v2) | ((unsigned)f2us(v3) << 16);
            pk.z = (unsigned)f2us(v4) | ((unsigned)f2us(v5) << 16);
            pk.w = (unsigned)f2us(v6) | ((unsigned)f2us(v7) << 16);
            *(uint4*)&KVb[gn * 16 + 8 * qq] = pk;
        }
    }
}

// Edge-parallel, pair-cooperative: 16 lanes/node = 8 edge slots x 2 sides; 2-deep prefetch.
__global__ __launch_bounds__(256) void k_l3_agg(const float* __restrict__ QS, const unsigned short* __restrict__ KVb,
                                                const int2* __restrict__ off2, const int* __restrict__ csr,
                                                float* __restrict__ out, int N) {
    int tid = threadIdx.x;
    int node = blockIdx.x * 16 + (tid >> 4);
    if (node >= N) return;
    int sl = tid & 15;
    int side = sl & 1;
    int p = sl >> 1;
    int lane = tid & 63;
    const float scale = 0.3779644730092272f;  // 1/sqrt(7)
    const float4* q4 = (const float4*)(QS + (size_t)node * 16);
    float4 qa = q4[0], qb = q4[1];
    qa.x *= scale; qa.y *= scale; qa.z *= scale; qa.w *= scale;
    qb.x *= scale; qb.y *= scale; qb.z *= scale; qb.w = 0.f;
    int2 ee = off2[node];

    float v[8];
#pragma unroll
    for (int i = 0; i < 8; ++i) v[i] = 0.f;

    int jj = ee.x + p;
    int sN = (jj < ee.y) ? csr[jj] : node;
    uint4 uN = *(const uint4*)(KVb + (size_t)sN * 16 + (side << 3));
    while (jj < ee.y) {
        uint4 u = uN;
        int jn = jj + 8;
        int s2 = (jn < ee.y) ? csr[jn] : node;
        uN = *(const uint4*)(KVb + (size_t)s2 * 16 + (side << 3));
        float t = 0.f;
        if (!side) {
            float k0 = __uint_as_float(u.x << 16), k1 = __uint_as_float(u.x & 0xFFFF0000u);
            float k2 = __uint_as_float(u.y << 16), k3 = __uint_as_float(u.y & 0xFFFF0000u);
            float k4 = __uint_as_float(u.z << 16), k5 = __uint_as_float(u.z & 0xFFFF0000u);
            float k6 = __uint_as_float(u.w << 16);
            t = qa.x * k0 + qa.y * k1 + qa.z * k2 + qa.w * k3
              + qb.x * k4 + qb.y * k5 + qb.z * k6;
        }
        float tf = __shfl_xor(t, 1);
        if (side) {
            float w = __expf(tf);
            v[0] += w * __uint_as_float(u.x << 16);
            v[1] += w * __uint_as_float(u.x & 0xFFFF0000u);
            v[2] += w * __uint_as_float(u.y << 16);
            v[3] += w * __uint_as_float(u.y & 0xFFFF0000u);
            v[4] += w * __uint_as_float(u.z << 16);
            v[5] += w * __uint_as_float(u.z & 0xFFFF0000u);
            v[6] += w * __uint_as_float(u.w << 16);
            v[7] += w;
        }
        jj = jn;
    }

#pragma unroll
    for (int d = 4; d >= 1; d >>= 1) {
#pragma unroll
        for (int i = 0; i < 8; ++i) {
            if (i < d) {
                float a = v[i], b = v[i + d];
                float send = (p & d) ? a : b;
                float recv = __shfl_xor(send, d << 1);
                v[i] = ((p & d) ? b : a) + recv;
            }
        }
    }
    float r = v[0];
    float den = __shfl(r, (lane & 48) | 15);
    if (side && p < 7) out[(size_t)node * 7 + p] = r / (den + 1e-16f)
                                                   + QS[(size_t)node * 16 + 8 + p];
}

// ---------------- launcher ----------------

extern "C" void kernel_launch(void* const* d_in, const int* in_sizes, int n_in,
                              void* d_out, int out_size, void* d_ws, size_t ws_size,
                              hipStream_t stream) {
    const int* ei = (const int*)d_in[1];
    float* out = (float*)d_out;

    int N = in_sizes[0] / 3;
    int E = in_sizes[1] / 2;
    int NB = (N + BMASK) >> BSH;        // assumed <= 512 (N <= 262144)
    int C = (E + NB - 1) / NB + 4096;

    char* ws = (char*)d_ws;
    size_t o = 0;
    auto take = [&](size_t bytes) -> char* {
        char* p = ws + o;
        o = (o + bytes + 255) & ~(size_t)255;
        return p;
    };
    int total_f = 0;
    for (int i = 2; i < 20; ++i) total_f += in_sizes[i];
    float* canon   = (float*)take((size_t)total_f * 4);
    unsigned short* Wp2h = (unsigned short*)take(4096 * 2);
    unsigned short* Wp2l = (unsigned short*)take(4096 * 2);
    unsigned short* Wp3h = (unsigned short*)take(1024 * 2);
    unsigned short* Wp3l = (unsigned short*)take(1024 * 2);
    float* bias64  = (float*)take(64 * 4);
    float* bcat    = (float*)take(32 * 4);
    float* Mfac    = (float*)take(32 * 4);
    int2*  off2    = (int2*)take((size_t)N * 8);
    int*   bcur    = (int*)take((512 * CUR_STRIDE + 1) * 4);
    int*   csr     = (int*)take((size_t)NB * C * 4);
    float* bufA    = (float*)take((size_t)N * 64 * 4);  // axs -> hlb|hr -> QS|KVb
    float* ad1     = (float*)take((size_t)N * 4 * 4);
    float* bufB    = (float*)take((size_t)N * 64 * 4);  // bkt -> x1 -> x2
    (void)ws_size; (void)n_in; (void)out_size;

    CvtArgs ca;
    const float* cp[20];
    {
        int off_ = 0, k = 0;
        for (int i = 0; i < 20; ++i) {
            if (i < 2) { cp[i] = nullptr; continue; }
            ca.p[k] = d_in[i];
            ca.sz[k] = in_sizes[i];
            cp[i] = canon + off_;
            off_ += in_sizes[i];
            ++k;
        }
    }

    int nbconv = (total_f + 255) / 256;
    k_convert<<<nbconv + 1, 256, 0, stream>>>(ca, (const unsigned short*)d_in[0], canon, total_f,
                                              nbconv, Wp2h, Wp2l, Wp3h, Wp3l, bias64, bcat, Mfac, bcur);
    const int* flagp = bcur + 512 * CUR_STRIDE;

    int* bkt = (int*)bufB;
    int gb = (E + 4095) / 4096;
    k_bscatter<<<gb, 1024, 0, stream>>>(ei, bcur, bkt, E, NB, C);

    float* axs = bufA;
    int nbl1 = (N + 511) >> 9;
    k_bbuild_l1t<<<NB + nbl1, 512, 0, stream>>>(bkt, bcur, off2, csr, d_in[0], flagp, Mfac,
                                                axs, ad1, N, NB, C);

    float* x1 = bufB;
    k_l1_agg<<<(N + 15) / 16, 256, 0, stream>>>(axs, (const float4*)ad1, off2, csr, cp[2], cp[5], x1, N);

    unsigned short* hlb = (unsigned short*)bufA;
    float* hr = bufA + (size_t)N * 16;
    k_l2_transform<<<(N + 63) / 64, 256, 0, stream>>>(x1, Wp2h, Wp2l, bias64, hlb, hr, N);
    float* x2 = bufB;
    k_l2_agg<<<(N + 15) / 16, 256, 0, stream>>>(hlb, hr, cp[10], cp[11], off2, csr, x2, N);

    float* QS = bufA;
    unsigned short* KVb = (unsigned short*)(bufA + (size_t)N * 16);
    k_l3_transform<<<(N + 63) / 64, 256, 0, stream>>>(x2, Wp3h, Wp3l, bcat, QS, KVb, N);
    k_l3_agg<<<(N + 15) / 16, 256, 0, stream>>>(QS, KVb, off2, csr, out, N);
}

// Round 5
// 229.108 us; speedup vs baseline: 3.0903x; 1.0014x over previous
//
#include <hip/hip_runtime.h>
#include <hip/hip_bf16.h>

typedef __hip_bfloat16 bf16;
typedef __attribute__((ext_vector_type(8))) short bf16x8;   // 8 bf16 (4 VGPRs) MFMA A/B frag
typedef __attribute__((ext_vector_type(4))) float f32x4;    // MFMA C/D frag

static __device__ __forceinline__ float us2f(unsigned short u) {
    union { unsigned int i; float f; } c; c.i = ((unsigned int)u) << 16; return c.f;
}
static __device__ __forceinline__ unsigned short f2us(float f) {
    union { float f; unsigned int i; } c; c.f = f;
    unsigned int r = c.i + 0x7FFF + ((c.i >> 16) & 1);   // round-to-nearest-even
    return (unsigned short)(r >> 16);
}

// wave-0 probe: is the float input stored as f32 (vs bf16)?
static __device__ __forceinline__ int probe_isf32(const unsigned short* xr, int* sflag) {
    int tid = threadIdx.x;
    if (tid < 64) {
        int bad = 0;
        for (int i = tid; i < 1024; i += 64) {
            int ex = (xr[2 * i] >> 7) & 0xFF;
            if (ex < 110 || ex > 135) bad++;
        }
#pragma unroll
        for (int m = 32; m >= 1; m >>= 1) bad += __shfl_xor(bad, m);
        if (tid == 0) *sflag = (bad > 256) ? 1 : 0;
    }
    __syncthreads();
    return *sflag;
}

static __device__ __forceinline__ int ld_edge(const int* er, size_t i, int idx64) {
    return idx64 ? er[2 * i] : er[i];
}

#define BSH 9
#define BMASK 511
#define CUR_STRIDE 16   // bucket cursors padded to 64B: no same-line atomic serialization

// ---------------- canonicalization + W-frag pack + bcur zero (fused) ----------------

struct CvtArgs { const void* p[18]; int sz[18]; };

static __device__ __forceinline__ float cvt_elem(const void* p, int off, int isf32) {
    return isf32 ? ((const float*)p)[off] : __bfloat162float(((const bf16*)p)[off]);
}

// blocks 0..nbconv-1: convert weight inputs to f32 canon.
// block nbconv: MFMA W-fragment packs (hi/lo split), bcat, bias64, Mfac, bcur zero, flag.
__global__ __launch_bounds__(256) void k_convert(CvtArgs a, const unsigned short* __restrict__ xraw,
                                                 float* __restrict__ dst, int total, int nbconv,
                                                 unsigned short* __restrict__ Wp2h, unsigned short* __restrict__ Wp2l,
                                                 unsigned short* __restrict__ Wp3h, unsigned short* __restrict__ Wp3l,
                                                 float* __restrict__ bias64,
                                                 float* __restrict__ bcat, float* __restrict__ Mfac,
                                                 int* __restrict__ bcur) {
    __shared__ int sflag;
    int isf32 = probe_isf32(xraw, &sflag);
    int tid = threadIdx.x;
    if ((int)blockIdx.x == nbconv) {
        // p-map: 0=W1 1=att_src1 2=att_dst1 3=b1 4=W2l 5=b2l 6=W2r 7=b2r 8=att2 9=b2
        //        10=Wq 11=bq 12=Wk 13=bk 14=Wv 15=bv 16=Wskip 17=bskip
        // Wp2 fragments: lane-ordered A/B frags for l2 MFMA. f = ((t4*2+s)*64+lane)*8+i
#pragma unroll
        for (int rr = 0; rr < 16; ++rr) {
            int f = rr * 256 + tid;             // 0..4095
            int i = f & 7, lane = (f >> 3) & 63, s = (f >> 9) & 1, t4 = f >> 10;
            int k = 32 * s + ((lane >> 4) << 3) + i;
            int c = 16 * t4 + (lane & 15);
            float w = (c < 32) ? cvt_elem(a.p[4], k * 32 + c, isf32)
                               : cvt_elem(a.p[6], k * 32 + (c - 32), isf32);
            unsigned short hb = f2us(w);
            Wp2h[f] = hb;
            Wp2l[f] = f2us(w - us2f(hb));
        }
        // Wp3 fragments: combined [Wq|Wskip|Wk|Wv] (each 7 cols + zero pad to 8)
#pragma unroll
        for (int rr = 0; rr < 4; ++rr) {
            int f = rr * 256 + tid;             // 0..1023
            int i = f & 7, lane = (f >> 3) & 63, t3 = f >> 9;
            int k = ((lane >> 4) << 3) + i;
            int c = 16 * t3 + (lane & 15);
            int g = c >> 3, cc = c & 7;
            const void* Wg = (g == 0) ? a.p[10] : (g == 1) ? a.p[16] : (g == 2) ? a.p[12] : a.p[14];
            float w = (cc < 7) ? cvt_elem(Wg, k * 7 + cc, isf32) : 0.f;
            unsigned short hb = f2us(w);
            Wp3h[f] = hb;
            Wp3l[f] = f2us(w - us2f(hb));
        }
        if (tid < 64) bias64[tid] = (tid < 32) ? cvt_elem(a.p[5], tid, isf32)
                                               : cvt_elem(a.p[7], tid - 32, isf32);
        if (tid < 32) {
            int g = tid >> 3, cc = tid & 7;
            const void* Bg = (g == 0) ? a.p[11] : (g == 1) ? a.p[17] : (g == 2) ? a.p[13] : a.p[15];
            bcat[tid] = (cc < 7) ? cvt_elem(Bg, cc, isf32) : 0.f;
        }
        // Mfac: Ms[k][H] = sum_c W1[k][16H+c]*att_src1[H][c]; Md with att_dst1.
        if (tid < 24) {
            int which = tid / 12;
            int r = tid % 12; int k = r >> 2, H = r & 3;
            const void* W1p = a.p[0];
            const void* ap = which ? a.p[2] : a.p[1];
            float s = 0.f;
            for (int c = 0; c < 16; ++c)
                s += cvt_elem(W1p, k * 64 + H * 16 + c, isf32) * cvt_elem(ap, H * 16 + c, isf32);
            Mfac[which * 16 + k * 4 + H] = s;
        }
        for (int i = tid; i < 512 * CUR_STRIDE + 1; i += 256) bcur[i] = 0;
        __syncthreads();
        if (tid == 0) bcur[512 * CUR_STRIDE] = isf32;
        return;
    }
    int t = blockIdx.x * 256 + tid;
    if (t >= total) return;
    int base = 0, seg = -1, off = 0;
#pragma unroll
    for (int i = 0; i < 18; i++) {
        if (seg < 0 && t < base + a.sz[i]) { seg = i; off = t - base; }
        base += a.sz[i];
    }
    dst[t] = cvt_elem(a.p[seg], off, isf32);
}

// ---------------- bucketed CSR build (512-node buckets; packed bkt) ----------------

__global__ __launch_bounds__(1024) void k_bscatter(const int* __restrict__ er,
                                                   int* __restrict__ bcur, int* __restrict__ bkt,
                                                   int E, int NB, int C) {
    __shared__ int cnt[512];
    __shared__ int res[512];
    __shared__ int sflag;
    int tid = threadIdx.x;
    if (tid < 64) {
        int lim = (E < 1024) ? E : 1024;
        int nz = 0;
        for (int i = tid; i < lim; i += 64) if (er[2 * i + 1] != 0) nz++;
#pragma unroll
        for (int m = 32; m >= 1; m >>= 1) nz += __shfl_xor(nz, m);
        if (tid == 0) sflag = (nz < ((E < 1024 ? E : 1024) >> 1)) ? 1 : 0;
    }
    if (tid < 512) cnt[tid] = 0;
    __syncthreads();
    int idx64 = sflag;
    int e0 = blockIdx.x * 4096 + tid * 4;
    int sv[4], dv[4];
    bool val[4];
    bool fast = (e0 + 4 <= E) && ((E & 3) == 0);
    if (fast) {
        const int4* p4 = (const int4*)er;
        if (idx64) {
            int4 u0 = p4[e0 >> 1], u1 = p4[(e0 >> 1) + 1];
            int4 w0 = p4[(E + e0) >> 1], w1 = p4[((E + e0) >> 1) + 1];
            sv[0] = u0.x; sv[1] = u0.z; sv[2] = u1.x; sv[3] = u1.z;
            dv[0] = w0.x; dv[1] = w0.z; dv[2] = w1.x; dv[3] = w1.z;
        } else {
            int4 u = p4[e0 >> 2];
            int4 w = p4[(E + e0) >> 2];
            sv[0] = u.x; sv[1] = u.y; sv[2] = u.z; sv[3] = u.w;
            dv[0] = w.x; dv[1] = w.y; dv[2] = w.z; dv[3] = w.w;
        }
#pragma unroll
        for (int k = 0; k < 4; ++k) val[k] = true;
    } else {
#pragma unroll
        for (int k = 0; k < 4; ++k) {
            int e = e0 + k;
            val[k] = (e < E);
            if (val[k]) {
                sv[k] = ld_edge(er, (size_t)e, idx64);
                dv[k] = ld_edge(er, (size_t)E + e, idx64);
            }
        }
    }
    int pk[4], bv[4];
#pragma unroll
    for (int k = 0; k < 4; ++k) {
        if (val[k]) {
            bv[k] = dv[k] >> BSH;
            pk[k] = (sv[k] << BSH) | (dv[k] & BMASK);
            atomicAdd(&cnt[bv[k]], 1);
        }
    }
    __syncthreads();
    if (tid < NB) {
        int c = cnt[tid];
        res[tid] = c ? atomicAdd(&bcur[tid * CUR_STRIDE], c) : 0;
        cnt[tid] = 0;
    }
    __syncthreads();
#pragma unroll
    for (int k = 0; k < 4; ++k) {
        if (val[k]) {
            int r = res[bv[k]] + atomicAdd(&cnt[bv[k]], 1);
            if (r < C) bkt[(size_t)bv[k] * C + r] = pk[k];
        }
    }
}

// blocks < NB: per-bucket indeg count + hierarchical wave-scan -> off2; scatter src -> csr.
// blocks >= NB: layer-1 transform (M-factored): axs = {x.Ms, x, 0}, ad1 = x.Md.
__global__ __launch_bounds__(512) void k_bbuild_l1t(const int* __restrict__ bkt, const int* __restrict__ bcur,
                                                    int2* __restrict__ off2, int* __restrict__ csr,
                                                    const void* __restrict__ xr, const int* __restrict__ flagp,
                                                    const float* __restrict__ Mfac,
                                                    float* __restrict__ axs, float* __restrict__ ad1,
                                                    int N, int NB, int C) {
    int tid = threadIdx.x;
    if ((int)blockIdx.x < NB) {
        __shared__ int sm[512];
        __shared__ int wsum[16];
        int b = blockIdx.x;
        size_t base = (size_t)b * C;
        int m = bcur[b * CUR_STRIDE]; if (m > C) m = C;
        const int* bp = bkt + base;
        int lane = tid & 63, wid = tid >> 6;
        sm[tid] = 0;
        __syncthreads();
        for (int i = tid; i < m; i += 512) atomicAdd(&sm[bp[i] & BMASK], 1);
        __syncthreads();
        int v = sm[tid];
        // hierarchical scan: per-wave inclusive shfl-scan; wave0 scans the 8 wave sums
        int x = v;
#pragma unroll
        for (int d = 1; d < 64; d <<= 1) {
            int t = __shfl_up(x, d);
            if (lane >= d) x += t;
        }
        if (lane == 63) wsum[wid] = x;
        __syncthreads();
        if (wid == 0) {
            int wv = (lane < 8) ? wsum[lane] : 0;
#pragma unroll
            for (int d = 1; d < 8; d <<= 1) {
                int t = __shfl_up(wv, d);
                if (lane >= d) wv += t;
            }
            if (lane < 8) wsum[8 + lane] = wv;
        }
        __syncthreads();
        int wbase = wid ? wsum[8 + wid - 1] : 0;
        int excl = x + wbase - v;
        int node = (b << BSH) + tid;
        if (node < N) off2[node] = make_int2((int)base + excl, (int)base + excl + v);
        __syncthreads();
        sm[tid] = excl;
        __syncthreads();
        for (int i = tid; i < m; i += 512) {
            int p = bp[i];
            int r = atomicAdd(&sm[p & BMASK], 1);
            csr[base + r] = p >> BSH;
        }
    } else {
        int isf32 = *flagp;
        float ms[12], md[12];
#pragma unroll
        for (int i = 0; i < 12; ++i) { ms[i] = Mfac[i]; md[i] = Mfac[16 + i]; }
        int node = ((int)blockIdx.x - NB) * 512 + tid;
        if (node < N) {
            float x0 = cvt_elem(xr, node * 3 + 0, isf32);
            float x1 = cvt_elem(xr, node * 3 + 1, isf32);
            float x2 = cvt_elem(xr, node * 3 + 2, isf32);
            float4 as, ad;
            as.x = x0 * ms[0] + x1 * ms[4] + x2 * ms[8];
            as.y = x0 * ms[1] + x1 * ms[5] + x2 * ms[9];
            as.z = x0 * ms[2] + x1 * ms[6] + x2 * ms[10];
            as.w = x0 * ms[3] + x1 * ms[7] + x2 * ms[11];
            ad.x = x0 * md[0] + x1 * md[4] + x2 * md[8];
            ad.y = x0 * md[1] + x1 * md[5] + x2 * md[9];
            ad.z = x0 * md[2] + x1 * md[6] + x2 * md[10];
            ad.w = x0 * md[3] + x1 * md[7] + x2 * md[11];
            *(float4*)&axs[(size_t)node * 8] = as;
            *(float4*)&axs[(size_t)node * 8 + 4] = make_float4(x0, x1, x2, 0.f);
            *(float4*)&ad1[(size_t)node * 4] = ad;
        }
    }
}

// ---------------- FUSED: Layer-1 agg (GATConv 3->16x4) -> Layer-2 transform (MFMA) ----------------
// 64 nodes/block. Phase 1: four 16-node groups run edge-parallel l1 aggregation (16 lanes/node),
// writing the 64-ch x1 row into LDS (no HBM round-trip). Phase 2: split-precision bf16 MFMA
// [64,64]x[64,64] producing hl (bf16) + hr (f32).

__global__ __launch_bounds__(256) void k_l1agg_l2t(const float* __restrict__ axs,
                                                   const float4* __restrict__ ad4p, const int2* __restrict__ off2,
                                                   const int* __restrict__ csr, const float* __restrict__ W1,
                                                   const float* __restrict__ b1,
                                                   const unsigned short* __restrict__ Wp2h,
                                                   const unsigned short* __restrict__ Wp2l,
                                                   const float* __restrict__ bias64,
                                                   unsigned short* __restrict__ hlb, float* __restrict__ hr, int N) {
    __shared__ float xs[64 * 68];
    int t = threadIdx.x;
    int node0 = blockIdx.x * 64;
    int nrem = N - node0; if (nrem > 64) nrem = 64;
    int sl = t & 15;
    int lane = t & 63;
    int lb = lane & 48;
    int ng = t >> 4;          // node-within-group 0..15

    // ---- phase 1: l1 aggregation, 4 groups of 16 nodes ----
    for (int gi = 0; gi < 4; ++gi) {
        int row = gi * 16 + ng;
        int node = node0 + row;
        if (node < N) {
            float4 ad = ad4p[node];
            int2 ee = off2[node];

            float v[16];
#pragma unroll
            for (int i = 0; i < 16; ++i) v[i] = 0.f;

            int jj = ee.x + sl;
            int sN = (jj < ee.y) ? csr[jj] : node;
            const float4* rpN = (const float4*)(axs + (size_t)sN * 8);
            float4 aN = rpN[0], xN = rpN[1];
            while (jj < ee.y) {
                float4 a = aN, xv = xN;
                int jn = jj + 16;
                int s2 = (jn < ee.y) ? csr[jn] : node;
                const float4* rp2 = (const float4*)(axs + (size_t)s2 * 8);
                aN = rp2[0]; xN = rp2[1];
                float z0 = a.x + ad.x, z1 = a.y + ad.y, z2 = a.z + ad.z, z3 = a.w + ad.w;
                z0 = (z0 > 0.f) ? z0 : 0.2f * z0;
                z1 = (z1 > 0.f) ? z1 : 0.2f * z1;
                z2 = (z2 > 0.f) ? z2 : 0.2f * z2;
                z3 = (z3 > 0.f) ? z3 : 0.2f * z3;
                float w0 = __expf(z0), w1 = __expf(z1), w2 = __expf(z2), w3 = __expf(z3);
                v[0] += w0 * xv.x; v[1] += w0 * xv.y; v[2]  += w0 * xv.z; v[3]  += w0;
                v[4] += w1 * xv.x; v[5] += w1 * xv.y; v[6]  += w1 * xv.z; v[7]  += w1;
                v[8] += w2 * xv.x; v[9] += w2 * xv.y; v[10] += w2 * xv.z; v[11] += w2;
                v[12] += w3 * xv.x; v[13] += w3 * xv.y; v[14] += w3 * xv.z; v[15] += w3;
                jj = jn;
            }

#pragma unroll
            for (int d = 8; d >= 1; d >>= 1) {
#pragma unroll
                for (int i = 0; i < 16; ++i) {
                    if (i < d) {
                        float a = v[i], b = v[i + d];
                        float send = (sl & d) ? a : b;
                        float recv = __shfl_xor(send, d);
                        v[i] = ((sl & d) ? b : a) + recv;
                    }
                }
            }
            float r = v[0];

            float agx[4], agy[4], agz[4], dn[4];
#pragma unroll
            for (int h = 0; h < 4; ++h) {
                agx[h] = __shfl(r, lb + 4 * h + 0);
                agy[h] = __shfl(r, lb + 4 * h + 1);
                agz[h] = __shfl(r, lb + 4 * h + 2);
                dn[h]  = __shfl(r, lb + 4 * h + 3);
            }

            {
                const float4* rp = (const float4*)(axs + (size_t)node * 8);
                float4 a = rp[0];
                float4 xv = rp[1];
                float z0 = a.x + ad.x, z1 = a.y + ad.y, z2 = a.z + ad.z, z3 = a.w + ad.w;
                z0 = (z0 > 0.f) ? z0 : 0.2f * z0;
                z1 = (z1 > 0.f) ? z1 : 0.2f * z1;
                z2 = (z2 > 0.f) ? z2 : 0.2f * z2;
                z3 = (z3 > 0.f) ? z3 : 0.2f * z3;
                float w0 = __expf(z0), w1 = __expf(z1), w2 = __expf(z2), w3 = __expf(z3);
                agx[0] += w0 * xv.x; agy[0] += w0 * xv.y; agz[0] += w0 * xv.z; dn[0] += w0;
                agx[1] += w1 * xv.x; agy[1] += w1 * xv.y; agz[1] += w1 * xv.z; dn[1] += w1;
                agx[2] += w2 * xv.x; agy[2] += w2 * xv.y; agz[2] += w2 * xv.z; dn[2] += w2;
                agx[3] += w3 * xv.x; agy[3] += w3 * xv.y; agz[3] += w3 * xv.z; dn[3] += w3;
            }

#pragma unroll
            for (int h = 0; h < 4; ++h) {
                int j = h * 16 + sl;
                float inv = 1.f / (dn[h] + 1e-16f);
                float o = (agx[h] * W1[j] + agy[h] * W1[64 + j] + agz[h] * W1[128 + j]) * inv + b1[j];
                xs[row * 68 + j] = (o > 0.f) ? o : 0.f;
            }
        }
    }
    __syncthreads();

    // ---- phase 2: split-precision MFMA transform (x1 tile already in LDS) ----
    int w = t >> 6;
    int rowl = 16 * w + (lane & 15);
    int koff = (lane >> 4) * 8;

    bf16x8 xh[2], xl[2];
#pragma unroll
    for (int s = 0; s < 2; ++s) {
#pragma unroll
        for (int i = 0; i < 8; ++i) {
            float v = xs[rowl * 68 + 32 * s + koff + i];
            unsigned short hb = f2us(v);
            xh[s][i] = (short)hb;
            xl[s][i] = (short)f2us(v - us2f(hb));
        }
    }

    const bf16x8* Wh = (const bf16x8*)Wp2h;
    const bf16x8* Wl = (const bf16x8*)Wp2l;
    f32x4 acc[4];
#pragma unroll
    for (int t4 = 0; t4 < 4; ++t4) {
        f32x4 a = {0.f, 0.f, 0.f, 0.f};
#pragma unroll
        for (int s = 0; s < 2; ++s) {
            bf16x8 wh = Wh[(t4 * 2 + s) * 64 + lane];
            bf16x8 wl = Wl[(t4 * 2 + s) * 64 + lane];
            a = __builtin_amdgcn_mfma_f32_16x16x32_bf16(xh[s], wh, a, 0, 0, 0);
            a = __builtin_amdgcn_mfma_f32_16x16x32_bf16(xl[s], wh, a, 0, 0, 0);
            a = __builtin_amdgcn_mfma_f32_16x16x32_bf16(xh[s], wl, a, 0, 0, 0);
        }
        acc[t4] = a;
    }

    __syncthreads();
#pragma unroll
    for (int t4 = 0; t4 < 4; ++t4) {
        float bb = bias64[16 * t4 + (lane & 15)];
        int col = 16 * t4 + (lane & 15);
#pragma unroll
        for (int r = 0; r < 4; ++r) {
            int rowm = 16 * w + (lane >> 4) * 4 + r;
            xs[rowm * 68 + col] = acc[t4][r] + bb;
        }
    }
    __syncthreads();

    int node = t >> 2, q = t & 3;
    if (node < nrem) {
        size_t gn = node0 + node;
        const float* row = &xs[node * 68];
        {
            float v0 = row[8 * q + 0], v1 = row[8 * q + 1], v2 = row[8 * q + 2], v3 = row[8 * q + 3];
            float v4 = row[8 * q + 4], v5 = row[8 * q + 5], v6 = row[8 * q + 6], v7 = row[8 * q + 7];
            uint4 pk;
            pk.x = (unsigned)f2us(v0) | ((unsigned)f2us(v1) << 16);
            pk.y = (unsigned)f2us(v2) | ((unsigned)f2us(v3) << 16);
            pk.z = (unsigned)f2us(v4) | ((unsigned)f2us(v5) << 16);
            pk.w = (unsigned)f2us(v6) | ((unsigned)f2us(v7) << 16);
            *(uint4*)&hlb[gn * 32 + 8 * q] = pk;
        }
        {
            float4 h0 = *(const float4*)&row[32 + 8 * q];
            float4 h1 = *(const float4*)&row[32 + 8 * q + 4];
            *(float4*)&hr[gn * 32 + 8 * q] = h0;
            *(float4*)&hr[gn * 32 + 8 * q + 4] = h1;
        }
    }
}

// ---------------- FUSED: Layer-2 agg (GATv2) -> Layer-3 transform (MFMA) ----------------
// 64 nodes/block. Phase 1: four 16-node groups (16 lanes/node = 4 edge slots x 4 channel-quarters),
// x2 row written to LDS. Phase 2: split-precision MFMA [64,32]x[32,32] -> QS (f32) + KVb (bf16).

__global__ __launch_bounds__(256) void k_l2agg_l3t(const unsigned short* __restrict__ hlb, const float* __restrict__ hr,
                                                   const float* __restrict__ att2, const float* __restrict__ b2,
                                                   const int2* __restrict__ off2, const int* __restrict__ csr,
                                                   const unsigned short* __restrict__ Wp3h,
                                                   const unsigned short* __restrict__ Wp3l,
                                                   const float* __restrict__ bcat,
                                                   float* __restrict__ QS, unsigned short* __restrict__ KVb, int N) {
    __shared__ float xs[64 * 36];
    int t = threadIdx.x;
    int node0 = blockIdx.x * 64;
    int nrem = N - node0; if (nrem > 64) nrem = 64;
    int sl = t & 15;
    int g = sl & 3;
    int slot = sl >> 2;
    int lane = t & 63;
    int ng = t >> 4;

    // ---- phase 1: l2 aggregation, 4 groups of 16 nodes ----
    for (int gi = 0; gi < 4; ++gi) {
        int row = gi * 16 + ng;
        int node = node0 + row;
        if (node < N) {
            float hrq[8], atq[8];
            {
                const float4* h4 = (const float4*)(hr + (size_t)node * 32 + g * 8);
                float4 h0 = h4[0], h1 = h4[1];
                hrq[0] = h0.x; hrq[1] = h0.y; hrq[2] = h0.z; hrq[3] = h0.w;
                hrq[4] = h1.x; hrq[5] = h1.y; hrq[6] = h1.z; hrq[7] = h1.w;
                const float4* a4 = (const float4*)(att2 + g * 8);
                float4 a0 = a4[0], a1 = a4[1];
                atq[0] = a0.x; atq[1] = a0.y; atq[2] = a0.z; atq[3] = a0.w;
                atq[4] = a1.x; atq[5] = a1.y; atq[6] = a1.z; atq[7] = a1.w;
            }
            int2 ee = off2[node];

            float acc[8];
#pragma unroll
            for (int j = 0; j < 8; ++j) acc[j] = 0.f;
            float den = 0.f;

            int jj = ee.x + slot;
            int sN = (jj < ee.y) ? csr[jj] : node;
            uint4 uN = *(const uint4*)(hlb + (size_t)sN * 32 + g * 8);
            while (jj < ee.y) {
                uint4 u = uN;
                int jn = jj + 4;
                int s2 = (jn < ee.y) ? csr[jn] : node;
                uN = *(const uint4*)(hlb + (size_t)s2 * 32 + g * 8);
                unsigned uu[4] = {u.x, u.y, u.z, u.w};
                float hlv[8];
#pragma unroll
                for (int q = 0; q < 4; ++q) {
                    hlv[2 * q]     = __uint_as_float(uu[q] << 16);
                    hlv[2 * q + 1] = __uint_as_float(uu[q] & 0xFFFF0000u);
                }
                float tt = 0.f;
#pragma unroll
                for (int j = 0; j < 8; ++j) {
                    float e = hlv[j] + hrq[j];
                    e = fmaxf(e, 0.2f * e);
                    tt += atq[j] * e;
                }
                tt += __shfl_xor(tt, 1);
                float w = __expf(tt);
                den += w;
#pragma unroll
                for (int j = 0; j < 8; ++j) acc[j] += w * hlv[j];
                jj = jn;
            }

            if (slot == 0) {
                uint4 u = *(const uint4*)(hlb + (size_t)node * 32 + g * 8);
                unsigned uu[4] = {u.x, u.y, u.z, u.w};
                float hlv[8];
#pragma unroll
                for (int q = 0; q < 4; ++q) {
                    hlv[2 * q]     = __uint_as_float(uu[q] << 16);
                    hlv[2 * q + 1] = __uint_as_float(uu[q] & 0xFFFF0000u);
                }
                float tt = 0.f;
#pragma unroll
                for (int j = 0; j < 8; ++j) {
                    float e = hlv[j] + hrq[j];
                    e = fmaxf(e, 0.2f * e);
                    tt += atq[j] * e;
                }
                tt += __shfl_xor(tt, 1);
                float w = __expf(tt);
                den += w;
#pragma unroll
                for (int j = 0; j < 8; ++j) acc[j] += w * hlv[j];
            }

#pragma unroll
            for (int d = 4; d <= 8; d <<= 1) {
#pragma unroll
                for (int j = 0; j < 8; ++j) acc[j] += __shfl_xor(acc[j], d);
                den += __shfl_xor(den, d);
            }

            if (slot < 2) {
                float inv = 1.f / (den + 1e-16f);
                int c = g * 8 + slot * 4;
                float4 bb = *(const float4*)(b2 + c);
                float o0 = slot ? acc[4] : acc[0];
                float o1 = slot ? acc[5] : acc[1];
                float o2 = slot ? acc[6] : acc[2];
                float o3 = slot ? acc[7] : acc[3];
                *(float4*)&xs[row * 36 + c] =
                    make_float4(o0 * inv + bb.x, o1 * inv + bb.y, o2 * inv + bb.z, o3 * inv + bb.w);
            }
        }
    }
    __syncthreads();

    // ---- phase 2: split-precision MFMA transform (x2 tile in LDS) ----
    int w = t >> 6;
    int rowl = 16 * w + (lane & 15);
    int koff = (lane >> 4) * 8;

    bf16x8 xh, xl;
#pragma unroll
    for (int i = 0; i < 8; ++i) {
        float v = xs[rowl * 36 + koff + i];
        unsigned short hb = f2us(v);
        xh[i] = (short)hb;
        xl[i] = (short)f2us(v - us2f(hb));
    }

    const bf16x8* Wh = (const bf16x8*)Wp3h;
    const bf16x8* Wl = (const bf16x8*)Wp3l;
    f32x4 acc[2];
#pragma unroll
    for (int t3 = 0; t3 < 2; ++t3) {
        f32x4 a = {0.f, 0.f, 0.f, 0.f};
        bf16x8 wh = Wh[t3 * 64 + lane];
        bf16x8 wl = Wl[t3 * 64 + lane];
        a = __builtin_amdgcn_mfma_f32_16x16x32_bf16(xh, wh, a, 0, 0, 0);
        a = __builtin_amdgcn_mfma_f32_16x16x32_bf16(xl, wh, a, 0, 0, 0);
        a = __builtin_amdgcn_mfma_f32_16x16x32_bf16(xh, wl, a, 0, 0, 0);
        acc[t3] = a;
    }

    __syncthreads();
#pragma unroll
    for (int t3 = 0; t3 < 2; ++t3) {
        float bb = bcat[16 * t3 + (lane & 15)];
        int col = 16 * t3 + (lane & 15);
#pragma unroll
        for (int r = 0; r < 4; ++r) {
            int rowm = 16 * w + (lane >> 4) * 4 + r;
            xs[rowm * 36 + col] = acc[t3][r] + bb;
        }
    }
    __syncthreads();

    int node = t >> 2, q = t & 3;
    if (node < nrem) {
        size_t gn = node0 + node;
        const float* row = &xs[node * 36];
        if (q < 2) {
            float4 h0 = *(const float4*)&row[8 * q];
            float4 h1 = *(const float4*)&row[8 * q + 4];
            *(float4*)(QS + gn * 16 + 8 * q) = h0;
            *(float4*)(QS + gn * 16 + 8 * q + 4) = h1;
        } else {
            int qq = q - 2;
            float v0 = row[16 + 8 * qq + 0], v1 = row[16 + 8 * qq + 1];
            float v2 = row[16 + 8 * qq + 2], v3 = row[16 + 8 * qq + 3];
            float v4 = row[16 + 8 * qq + 4], v5 = row[16 + 8 * qq + 5];
            float v6 = row[16 + 8 * qq + 6], v7 = row[16 + 8 * qq + 7];
            uint4 pk;
            pk.x = (unsigned)f2us(v0) | ((unsigned)f2us(v1) << 16);
            pk.y = (unsigned)f2us(v2) | ((unsigned)f2us(v3) << 16);
            pk.z = (unsigned)f2us(v4) | ((unsigned)f2us(v5) << 16);
            pk.w = (unsigned)f2us(v6) | ((unsigned)f2us(v7) << 16);
            *(uint4*)&KVb[gn * 16 + 8 * qq] = pk;
        }
    }
}

// ---------------- Layer 3 agg: TransformerConv(32, 7, heads=1) ----------------
// Edge-parallel, pair-cooperative: 16 lanes/node = 8 edge slots x 2 sides; 2-deep prefetch.
__global__ __launch_bounds__(256) void k_l3_agg(const float* __restrict__ QS, const unsigned short* __restrict__ KVb,
                                                const int2* __restrict__ off2, const int* __restrict__ csr,
                                                float* __restrict__ out, int N) {
    int tid = threadIdx.x;
    int node = blockIdx.x * 16 + (tid >> 4);
    if (node >= N) return;
    int sl = tid & 15;
    int side = sl & 1;
    int p = sl >> 1;
    int lane = tid & 63;
    const float scale = 0.3779644730092272f;  // 1/sqrt(7)
    const float4* q4 = (const float4*)(QS + (size_t)node * 16);
    float4 qa = q4[0], qb = q4[1];
    qa.x *= scale; qa.y *= scale; qa.z *= scale; qa.w *= scale;
    qb.x *= scale; qb.y *= scale; qb.z *= scale; qb.w = 0.f;
    int2 ee = off2[node];

    float v[8];
#pragma unroll
    for (int i = 0; i < 8; ++i) v[i] = 0.f;

    int jj = ee.x + p;
    int sN = (jj < ee.y) ? csr[jj] : node;
    uint4 uN = *(const uint4*)(KVb + (size_t)sN * 16 + (side << 3));
    while (jj < ee.y) {
        uint4 u = uN;
        int jn = jj + 8;
        int s2 = (jn < ee.y) ? csr[jn] : node;
        uN = *(const uint4*)(KVb + (size_t)s2 * 16 + (side << 3));
        float t = 0.f;
        if (!side) {
            float k0 = __uint_as_float(u.x << 16), k1 = __uint_as_float(u.x & 0xFFFF0000u);
            float k2 = __uint_as_float(u.y << 16), k3 = __uint_as_float(u.y & 0xFFFF0000u);
            float k4 = __uint_as_float(u.z << 16), k5 = __uint_as_float(u.z & 0xFFFF0000u);
            float k6 = __uint_as_float(u.w << 16);
            t = qa.x * k0 + qa.y * k1 + qa.z * k2 + qa.w * k3
              + qb.x * k4 + qb.y * k5 + qb.z * k6;
        }
        float tf = __shfl_xor(t, 1);
        if (side) {
            float w = __expf(tf);
            v[0] += w * __uint_as_float(u.x << 16);
            v[1] += w * __uint_as_float(u.x & 0xFFFF0000u);
            v[2] += w * __uint_as_float(u.y << 16);
            v[3] += w * __uint_as_float(u.y & 0xFFFF0000u);
            v[4] += w * __uint_as_float(u.z << 16);
            v[5] += w * __uint_as_float(u.z & 0xFFFF0000u);
            v[6] += w * __uint_as_float(u.w << 16);
            v[7] += w;
        }
        jj = jn;
    }

#pragma unroll
    for (int d = 4; d >= 1; d >>= 1) {
#pragma unroll
        for (int i = 0; i < 8; ++i) {
            if (i < d) {
                float a = v[i], b = v[i + d];
                float send = (p & d) ? a : b;
                float recv = __shfl_xor(send, d << 1);
                v[i] = ((p & d) ? b : a) + recv;
            }
        }
    }
    float r = v[0];
    float den = __shfl(r, (lane & 48) | 15);
    if (side && p < 7) out[(size_t)node * 7 + p] = r / (den + 1e-16f)
                                                   + QS[(size_t)node * 16 + 8 + p];
}

// ---------------- launcher ----------------

extern "C" void kernel_launch(void* const* d_in, const int* in_sizes, int n_in,
                              void* d_out, int out_size, void* d_ws, size_t ws_size,
                              hipStream_t stream) {
    const int* ei = (const int*)d_in[1];
    float* out = (float*)d_out;

    int N = in_sizes[0] / 3;
    int E = in_sizes[1] / 2;
    int NB = (N + BMASK) >> BSH;        // assumed <= 512 (N <= 262144)
    int C = (E + NB - 1) / NB + 4096;

    char* ws = (char*)d_ws;
    size_t o = 0;
    auto take = [&](size_t bytes) -> char* {
        char* p = ws + o;
        o = (o + bytes + 255) & ~(size_t)255;
        return p;
    };
    int total_f = 0;
    for (int i = 2; i < 20; ++i) total_f += in_sizes[i];
    float* canon   = (float*)take((size_t)total_f * 4);
    unsigned short* Wp2h = (unsigned short*)take(4096 * 2);
    unsigned short* Wp2l = (unsigned short*)take(4096 * 2);
    unsigned short* Wp3h = (unsigned short*)take(1024 * 2);
    unsigned short* Wp3l = (unsigned short*)take(1024 * 2);
    float* bias64  = (float*)take(64 * 4);
    float* bcat    = (float*)take(32 * 4);
    float* Mfac    = (float*)take(32 * 4);
    int2*  off2    = (int2*)take((size_t)N * 8);
    int*   bcur    = (int*)take((512 * CUR_STRIDE + 1) * 4);
    int*   csr     = (int*)take((size_t)NB * C * 4);
    float* bufA    = (float*)take((size_t)N * 64 * 4);  // axs -> QS|KVb
    float* ad1     = (float*)take((size_t)N * 4 * 4);
    float* bufB    = (float*)take((size_t)N * 64 * 4);  // bkt -> hlb|hr
    (void)ws_size; (void)n_in; (void)out_size;

    CvtArgs ca;
    const float* cp[20];
    {
        int off_ = 0, k = 0;
        for (int i = 0; i < 20; ++i) {
            if (i < 2) { cp[i] = nullptr; continue; }
            ca.p[k] = d_in[i];
            ca.sz[k] = in_sizes[i];
            cp[i] = canon + off_;
            off_ += in_sizes[i];
            ++k;
        }
    }

    int nbconv = (total_f + 255) / 256;
    k_convert<<<nbconv + 1, 256, 0, stream>>>(ca, (const unsigned short*)d_in[0], canon, total_f,
                                              nbconv, Wp2h, Wp2l, Wp3h, Wp3l, bias64, bcat, Mfac, bcur);
    const int* flagp = bcur + 512 * CUR_STRIDE;

    // bkt aliases bufB; dead after k_bbuild_l1t, then bufB holds hlb|hr
    int* bkt = (int*)bufB;
    int gb = (E + 4095) / 4096;
    k_bscatter<<<gb, 1024, 0, stream>>>(ei, bcur, bkt, E, NB, C);

    float* axs = bufA;
    int nbl1 = (N + 511) >> 9;
    k_bbuild_l1t<<<NB + nbl1, 512, 0, stream>>>(bkt, bcur, off2, csr, d_in[0], flagp, Mfac,
                                                axs, ad1, N, NB, C);

    // fused l1_agg + l2_transform: reads axs (bufA), writes hlb|hr (bufB)
    unsigned short* hlb = (unsigned short*)bufB;                 // N*32 bf16 = 6.4 MB
    float* hr = bufB + (size_t)N * 16;                           // N*32 f32 = 12.8 MB
    k_l1agg_l2t<<<(N + 63) / 64, 256, 0, stream>>>(axs, (const float4*)ad1, off2, csr,
                                                   cp[2], cp[5], Wp2h, Wp2l, bias64, hlb, hr, N);

    // fused l2_agg + l3_transform: reads hlb|hr (bufB), writes QS|KVb (bufA; axs dead)
    float* QS = bufA;                                            // N*16 f32
    unsigned short* KVb = (unsigned short*)(bufA + (size_t)N * 16);  // N*16 bf16 = 3.2 MB
    k_l2agg_l3t<<<(N + 63) / 64, 256, 0, stream>>>(hlb, hr, cp[10], cp[11], off2, csr,
                                                   Wp3h, Wp3l, bcat, QS, KVb, N);

    k_l3_agg<<<(N + 15) / 16, 256, 0, stream>>>(QS, KVb, off2, csr, out, N);
}

// Round 6
// 222.361 us; speedup vs baseline: 3.1841x; 1.0303x over previous
//
#include <hip/hip_runtime.h>
#include <hip/hip_bf16.h>

typedef __hip_bfloat16 bf16;
typedef __attribute__((ext_vector_type(8))) short bf16x8;   // 8 bf16 (4 VGPRs) MFMA A/B frag
typedef __attribute__((ext_vector_type(4))) float f32x4;    // MFMA C/D frag

static __device__ __forceinline__ float us2f(unsigned short u) {
    union { unsigned int i; float f; } c; c.i = ((unsigned int)u) << 16; return c.f;
}
static __device__ __forceinline__ unsigned short f2us(float f) {
    union { float f; unsigned int i; } c; c.f = f;
    unsigned int r = c.i + 0x7FFF + ((c.i >> 16) & 1);   // round-to-nearest-even
    return (unsigned short)(r >> 16);
}

// wave-0 probe: is the float input stored as f32 (vs bf16)?
static __device__ __forceinline__ int probe_isf32(const unsigned short* xr, int* sflag) {
    int tid = threadIdx.x;
    if (tid < 64) {
        int bad = 0;
        for (int i = tid; i < 1024; i += 64) {
            int ex = (xr[2 * i] >> 7) & 0xFF;
            if (ex < 110 || ex > 135) bad++;
        }
#pragma unroll
        for (int m = 32; m >= 1; m >>= 1) bad += __shfl_xor(bad, m);
        if (tid == 0) *sflag = (bad > 256) ? 1 : 0;
    }
    __syncthreads();
    return *sflag;
}

static __device__ __forceinline__ int ld_edge(const int* er, size_t i, int idx64) {
    return idx64 ? er[2 * i] : er[i];
}

#define BSH 9
#define BMASK 511
#define CUR_STRIDE 16   // bucket cursors padded to 64B: no same-line atomic serialization

// ---------------- canonicalization + W-frag pack + bcur zero (fused) ----------------

struct CvtArgs { const void* p[18]; int sz[18]; };

static __device__ __forceinline__ float cvt_elem(const void* p, int off, int isf32) {
    return isf32 ? ((const float*)p)[off] : __bfloat162float(((const bf16*)p)[off]);
}

// blocks 0..nbconv-1: convert weight inputs to f32 canon.
// block nbconv: MFMA W-fragment packs (hi/lo split), bcat, bias64, Mfac, bcur zero, flag.
__global__ __launch_bounds__(256) void k_convert(CvtArgs a, const unsigned short* __restrict__ xraw,
                                                 float* __restrict__ dst, int total, int nbconv,
                                                 unsigned short* __restrict__ Wp2h, unsigned short* __restrict__ Wp2l,
                                                 unsigned short* __restrict__ Wp3h, unsigned short* __restrict__ Wp3l,
                                                 float* __restrict__ bias64,
                                                 float* __restrict__ bcat, float* __restrict__ Mfac,
                                                 int* __restrict__ bcur) {
    __shared__ int sflag;
    int isf32 = probe_isf32(xraw, &sflag);
    int tid = threadIdx.x;
    if ((int)blockIdx.x == nbconv) {
        // p-map: 0=W1 1=att_src1 2=att_dst1 3=b1 4=W2l 5=b2l 6=W2r 7=b2r 8=att2 9=b2
        //        10=Wq 11=bq 12=Wk 13=bk 14=Wv 15=bv 16=Wskip 17=bskip
        // Wp2 fragments: lane-ordered A/B frags for l2 MFMA. f = ((t4*2+s)*64+lane)*8+i
#pragma unroll
        for (int rr = 0; rr < 16; ++rr) {
            int f = rr * 256 + tid;             // 0..4095
            int i = f & 7, lane = (f >> 3) & 63, s = (f >> 9) & 1, t4 = f >> 10;
            int k = 32 * s + ((lane >> 4) << 3) + i;
            int c = 16 * t4 + (lane & 15);
            float w = (c < 32) ? cvt_elem(a.p[4], k * 32 + c, isf32)
                               : cvt_elem(a.p[6], k * 32 + (c - 32), isf32);
            unsigned short hb = f2us(w);
            Wp2h[f] = hb;
            Wp2l[f] = f2us(w - us2f(hb));
        }
        // Wp3 fragments: combined [Wq|Wskip|Wk|Wv] (each 7 cols + zero pad to 8)
#pragma unroll
        for (int rr = 0; rr < 4; ++rr) {
            int f = rr * 256 + tid;             // 0..1023
            int i = f & 7, lane = (f >> 3) & 63, t3 = f >> 9;
            int k = ((lane >> 4) << 3) + i;
            int c = 16 * t3 + (lane & 15);
            int g = c >> 3, cc = c & 7;
            const void* Wg = (g == 0) ? a.p[10] : (g == 1) ? a.p[16] : (g == 2) ? a.p[12] : a.p[14];
            float w = (cc < 7) ? cvt_elem(Wg, k * 7 + cc, isf32) : 0.f;
            unsigned short hb = f2us(w);
            Wp3h[f] = hb;
            Wp3l[f] = f2us(w - us2f(hb));
        }
        if (tid < 64) bias64[tid] = (tid < 32) ? cvt_elem(a.p[5], tid, isf32)
                                               : cvt_elem(a.p[7], tid - 32, isf32);
        if (tid < 32) {
            int g = tid >> 3, cc = tid & 7;
            const void* Bg = (g == 0) ? a.p[11] : (g == 1) ? a.p[17] : (g == 2) ? a.p[13] : a.p[15];
            bcat[tid] = (cc < 7) ? cvt_elem(Bg, cc, isf32) : 0.f;
        }
        // Mfac: Ms[k][H] = sum_c W1[k][16H+c]*att_src1[H][c]; Md with att_dst1.
        if (tid < 24) {
            int which = tid / 12;
            int r = tid % 12; int k = r >> 2, H = r & 3;
            const void* W1p = a.p[0];
            const void* ap = which ? a.p[2] : a.p[1];
            float s = 0.f;
            for (int c = 0; c < 16; ++c)
                s += cvt_elem(W1p, k * 64 + H * 16 + c, isf32) * cvt_elem(ap, H * 16 + c, isf32);
            Mfac[which * 16 + k * 4 + H] = s;
        }
        for (int i = tid; i < 512 * CUR_STRIDE + 1; i += 256) bcur[i] = 0;
        __syncthreads();
        if (tid == 0) bcur[512 * CUR_STRIDE] = isf32;
        return;
    }
    int t = blockIdx.x * 256 + tid;
    if (t >= total) return;
    int base = 0, seg = -1, off = 0;
#pragma unroll
    for (int i = 0; i < 18; i++) {
        if (seg < 0 && t < base + a.sz[i]) { seg = i; off = t - base; }
        base += a.sz[i];
    }
    dst[t] = cvt_elem(a.p[seg], off, isf32);
}

// ---------------- bucketed CSR build (512-node buckets; packed bkt) ----------------

__global__ __launch_bounds__(1024) void k_bscatter(const int* __restrict__ er,
                                                   int* __restrict__ bcur, int* __restrict__ bkt,
                                                   int E, int NB, int C) {
    __shared__ int cnt[512];
    __shared__ int res[512];
    __shared__ int sflag;
    int tid = threadIdx.x;
    if (tid < 64) {
        int lim = (E < 1024) ? E : 1024;
        int nz = 0;
        for (int i = tid; i < lim; i += 64) if (er[2 * i + 1] != 0) nz++;
#pragma unroll
        for (int m = 32; m >= 1; m >>= 1) nz += __shfl_xor(nz, m);
        if (tid == 0) sflag = (nz < ((E < 1024 ? E : 1024) >> 1)) ? 1 : 0;
    }
    if (tid < 512) cnt[tid] = 0;
    __syncthreads();
    int idx64 = sflag;
    int e0 = blockIdx.x * 4096 + tid * 4;
    int sv[4], dv[4];
    bool val[4];
    bool fast = (e0 + 4 <= E) && ((E & 3) == 0);
    if (fast) {
        const int4* p4 = (const int4*)er;
        if (idx64) {
            int4 u0 = p4[e0 >> 1], u1 = p4[(e0 >> 1) + 1];
            int4 w0 = p4[(E + e0) >> 1], w1 = p4[((E + e0) >> 1) + 1];
            sv[0] = u0.x; sv[1] = u0.z; sv[2] = u1.x; sv[3] = u1.z;
            dv[0] = w0.x; dv[1] = w0.z; dv[2] = w1.x; dv[3] = w1.z;
        } else {
            int4 u = p4[e0 >> 2];
            int4 w = p4[(E + e0) >> 2];
            sv[0] = u.x; sv[1] = u.y; sv[2] = u.z; sv[3] = u.w;
            dv[0] = w.x; dv[1] = w.y; dv[2] = w.z; dv[3] = w.w;
        }
#pragma unroll
        for (int k = 0; k < 4; ++k) val[k] = true;
    } else {
#pragma unroll
        for (int k = 0; k < 4; ++k) {
            int e = e0 + k;
            val[k] = (e < E);
            if (val[k]) {
                sv[k] = ld_edge(er, (size_t)e, idx64);
                dv[k] = ld_edge(er, (size_t)E + e, idx64);
            }
        }
    }
    int pk[4], bv[4];
#pragma unroll
    for (int k = 0; k < 4; ++k) {
        if (val[k]) {
            bv[k] = dv[k] >> BSH;
            pk[k] = (sv[k] << BSH) | (dv[k] & BMASK);
            atomicAdd(&cnt[bv[k]], 1);
        }
    }
    __syncthreads();
    if (tid < NB) {
        int c = cnt[tid];
        res[tid] = c ? atomicAdd(&bcur[tid * CUR_STRIDE], c) : 0;
        cnt[tid] = 0;
    }
    __syncthreads();
#pragma unroll
    for (int k = 0; k < 4; ++k) {
        if (val[k]) {
            int r = res[bv[k]] + atomicAdd(&cnt[bv[k]], 1);
            if (r < C) bkt[(size_t)bv[k] * C + r] = pk[k];
        }
    }
}

// blocks < NB: per-bucket indeg count + hierarchical wave-scan -> off2; scatter src -> csr.
// blocks >= NB: layer-1 transform (M-factored): axs = {x.Ms, x, 0}, ad1 = x.Md.
__global__ __launch_bounds__(512) void k_bbuild_l1t(const int* __restrict__ bkt, const int* __restrict__ bcur,
                                                    int2* __restrict__ off2, int* __restrict__ csr,
                                                    const void* __restrict__ xr, const int* __restrict__ flagp,
                                                    const float* __restrict__ Mfac,
                                                    float* __restrict__ axs, float* __restrict__ ad1,
                                                    int N, int NB, int C) {
    int tid = threadIdx.x;
    if ((int)blockIdx.x < NB) {
        __shared__ int sm[512];
        __shared__ int wsum[16];
        int b = blockIdx.x;
        size_t base = (size_t)b * C;
        int m = bcur[b * CUR_STRIDE]; if (m > C) m = C;
        const int* bp = bkt + base;
        int lane = tid & 63, wid = tid >> 6;
        sm[tid] = 0;
        __syncthreads();
        for (int i = tid; i < m; i += 512) atomicAdd(&sm[bp[i] & BMASK], 1);
        __syncthreads();
        int v = sm[tid];
        // hierarchical scan: per-wave inclusive shfl-scan; wave0 scans the 8 wave sums
        int x = v;
#pragma unroll
        for (int d = 1; d < 64; d <<= 1) {
            int t = __shfl_up(x, d);
            if (lane >= d) x += t;
        }
        if (lane == 63) wsum[wid] = x;
        __syncthreads();
        if (wid == 0) {
            int wv = (lane < 8) ? wsum[lane] : 0;
#pragma unroll
            for (int d = 1; d < 8; d <<= 1) {
                int t = __shfl_up(wv, d);
                if (lane >= d) wv += t;
            }
            if (lane < 8) wsum[8 + lane] = wv;
        }
        __syncthreads();
        int wbase = wid ? wsum[8 + wid - 1] : 0;
        int excl = x + wbase - v;
        int node = (b << BSH) + tid;
        if (node < N) off2[node] = make_int2((int)base + excl, (int)base + excl + v);
        __syncthreads();
        sm[tid] = excl;
        __syncthreads();
        for (int i = tid; i < m; i += 512) {
            int p = bp[i];
            int r = atomicAdd(&sm[p & BMASK], 1);
            csr[base + r] = p >> BSH;
        }
    } else {
        int isf32 = *flagp;
        float ms[12], md[12];
#pragma unroll
        for (int i = 0; i < 12; ++i) { ms[i] = Mfac[i]; md[i] = Mfac[16 + i]; }
        int node = ((int)blockIdx.x - NB) * 512 + tid;
        if (node < N) {
            float x0 = cvt_elem(xr, node * 3 + 0, isf32);
            float x1 = cvt_elem(xr, node * 3 + 1, isf32);
            float x2 = cvt_elem(xr, node * 3 + 2, isf32);
            float4 as, ad;
            as.x = x0 * ms[0] + x1 * ms[4] + x2 * ms[8];
            as.y = x0 * ms[1] + x1 * ms[5] + x2 * ms[9];
            as.z = x0 * ms[2] + x1 * ms[6] + x2 * ms[10];
            as.w = x0 * ms[3] + x1 * ms[7] + x2 * ms[11];
            ad.x = x0 * md[0] + x1 * md[4] + x2 * md[8];
            ad.y = x0 * md[1] + x1 * md[5] + x2 * md[9];
            ad.z = x0 * md[2] + x1 * md[6] + x2 * md[10];
            ad.w = x0 * md[3] + x1 * md[7] + x2 * md[11];
            *(float4*)&axs[(size_t)node * 8] = as;
            *(float4*)&axs[(size_t)node * 8 + 4] = make_float4(x0, x1, x2, 0.f);
            *(float4*)&ad1[(size_t)node * 4] = ad;
        }
    }
}

// ---------------- FUSED: Layer-1 agg (GATConv 3->16x4) -> Layer-2 transform (MFMA) ----------------
// Kept from r5 (netted ~ -8us): 64 nodes/block, phase-1 aggregation into LDS, phase-2 MFMA.

__global__ __launch_bounds__(256) void k_l1agg_l2t(const float* __restrict__ axs,
                                                   const float4* __restrict__ ad4p, const int2* __restrict__ off2,
                                                   const int* __restrict__ csr, const float* __restrict__ W1,
                                                   const float* __restrict__ b1,
                                                   const unsigned short* __restrict__ Wp2h,
                                                   const unsigned short* __restrict__ Wp2l,
                                                   const float* __restrict__ bias64,
                                                   unsigned short* __restrict__ hlb, float* __restrict__ hr, int N) {
    __shared__ float xs[64 * 68];
    int t = threadIdx.x;
    int node0 = blockIdx.x * 64;
    int nrem = N - node0; if (nrem > 64) nrem = 64;
    int sl = t & 15;
    int lane = t & 63;
    int lb = lane & 48;
    int ng = t >> 4;          // node-within-group 0..15

    // ---- phase 1: l1 aggregation, 4 groups of 16 nodes ----
    for (int gi = 0; gi < 4; ++gi) {
        int row = gi * 16 + ng;
        int node = node0 + row;
        if (node < N) {
            float4 ad = ad4p[node];
            int2 ee = off2[node];

            float v[16];
#pragma unroll
            for (int i = 0; i < 16; ++i) v[i] = 0.f;

            int jj = ee.x + sl;
            int sN = (jj < ee.y) ? csr[jj] : node;
            const float4* rpN = (const float4*)(axs + (size_t)sN * 8);
            float4 aN = rpN[0], xN = rpN[1];
            while (jj < ee.y) {
                float4 a = aN, xv = xN;
                int jn = jj + 16;
                int s2 = (jn < ee.y) ? csr[jn] : node;
                const float4* rp2 = (const float4*)(axs + (size_t)s2 * 8);
                aN = rp2[0]; xN = rp2[1];
                float z0 = a.x + ad.x, z1 = a.y + ad.y, z2 = a.z + ad.z, z3 = a.w + ad.w;
                z0 = (z0 > 0.f) ? z0 : 0.2f * z0;
                z1 = (z1 > 0.f) ? z1 : 0.2f * z1;
                z2 = (z2 > 0.f) ? z2 : 0.2f * z2;
                z3 = (z3 > 0.f) ? z3 : 0.2f * z3;
                float w0 = __expf(z0), w1 = __expf(z1), w2 = __expf(z2), w3 = __expf(z3);
                v[0] += w0 * xv.x; v[1] += w0 * xv.y; v[2]  += w0 * xv.z; v[3]  += w0;
                v[4] += w1 * xv.x; v[5] += w1 * xv.y; v[6]  += w1 * xv.z; v[7]  += w1;
                v[8] += w2 * xv.x; v[9] += w2 * xv.y; v[10] += w2 * xv.z; v[11] += w2;
                v[12] += w3 * xv.x; v[13] += w3 * xv.y; v[14] += w3 * xv.z; v[15] += w3;
                jj = jn;
            }

#pragma unroll
            for (int d = 8; d >= 1; d >>= 1) {
#pragma unroll
                for (int i = 0; i < 16; ++i) {
                    if (i < d) {
                        float a = v[i], b = v[i + d];
                        float send = (sl & d) ? a : b;
                        float recv = __shfl_xor(send, d);
                        v[i] = ((sl & d) ? b : a) + recv;
                    }
                }
            }
            float r = v[0];

            float agx[4], agy[4], agz[4], dn[4];
#pragma unroll
            for (int h = 0; h < 4; ++h) {
                agx[h] = __shfl(r, lb + 4 * h + 0);
                agy[h] = __shfl(r, lb + 4 * h + 1);
                agz[h] = __shfl(r, lb + 4 * h + 2);
                dn[h]  = __shfl(r, lb + 4 * h + 3);
            }

            {
                const float4* rp = (const float4*)(axs + (size_t)node * 8);
                float4 a = rp[0];
                float4 xv = rp[1];
                float z0 = a.x + ad.x, z1 = a.y + ad.y, z2 = a.z + ad.z, z3 = a.w + ad.w;
                z0 = (z0 > 0.f) ? z0 : 0.2f * z0;
                z1 = (z1 > 0.f) ? z1 : 0.2f * z1;
                z2 = (z2 > 0.f) ? z2 : 0.2f * z2;
                z3 = (z3 > 0.f) ? z3 : 0.2f * z3;
                float w0 = __expf(z0), w1 = __expf(z1), w2 = __expf(z2), w3 = __expf(z3);
                agx[0] += w0 * xv.x; agy[0] += w0 * xv.y; agz[0] += w0 * xv.z; dn[0] += w0;
                agx[1] += w1 * xv.x; agy[1] += w1 * xv.y; agz[1] += w1 * xv.z; dn[1] += w1;
                agx[2] += w2 * xv.x; agy[2] += w2 * xv.y; agz[2] += w2 * xv.z; dn[2] += w2;
                agx[3] += w3 * xv.x; agy[3] += w3 * xv.y; agz[3] += w3 * xv.z; dn[3] += w3;
            }

#pragma unroll
            for (int h = 0; h < 4; ++h) {
                int j = h * 16 + sl;
                float inv = 1.f / (dn[h] + 1e-16f);
                float o = (agx[h] * W1[j] + agy[h] * W1[64 + j] + agz[h] * W1[128 + j]) * inv + b1[j];
                xs[row * 68 + j] = (o > 0.f) ? o : 0.f;
            }
        }
    }
    __syncthreads();

    // ---- phase 2: split-precision MFMA transform (x1 tile already in LDS) ----
    int w = t >> 6;
    int rowl = 16 * w + (lane & 15);
    int koff = (lane >> 4) * 8;

    bf16x8 xh[2], xl[2];
#pragma unroll
    for (int s = 0; s < 2; ++s) {
#pragma unroll
        for (int i = 0; i < 8; ++i) {
            float v = xs[rowl * 68 + 32 * s + koff + i];
            unsigned short hb = f2us(v);
            xh[s][i] = (short)hb;
            xl[s][i] = (short)f2us(v - us2f(hb));
        }
    }

    const bf16x8* Wh = (const bf16x8*)Wp2h;
    const bf16x8* Wl = (const bf16x8*)Wp2l;
    f32x4 acc[4];
#pragma unroll
    for (int t4 = 0; t4 < 4; ++t4) {
        f32x4 a = {0.f, 0.f, 0.f, 0.f};
#pragma unroll
        for (int s = 0; s < 2; ++s) {
            bf16x8 wh = Wh[(t4 * 2 + s) * 64 + lane];
            bf16x8 wl = Wl[(t4 * 2 + s) * 64 + lane];
            a = __builtin_amdgcn_mfma_f32_16x16x32_bf16(xh[s], wh, a, 0, 0, 0);
            a = __builtin_amdgcn_mfma_f32_16x16x32_bf16(xl[s], wh, a, 0, 0, 0);
            a = __builtin_amdgcn_mfma_f32_16x16x32_bf16(xh[s], wl, a, 0, 0, 0);
        }
        acc[t4] = a;
    }

    __syncthreads();
#pragma unroll
    for (int t4 = 0; t4 < 4; ++t4) {
        float bb = bias64[16 * t4 + (lane & 15)];
        int col = 16 * t4 + (lane & 15);
#pragma unroll
        for (int r = 0; r < 4; ++r) {
            int rowm = 16 * w + (lane >> 4) * 4 + r;
            xs[rowm * 68 + col] = acc[t4][r] + bb;
        }
    }
    __syncthreads();

    int node = t >> 2, q = t & 3;
    if (node < nrem) {
        size_t gn = node0 + node;
        const float* row = &xs[node * 68];
        {
            float v0 = row[8 * q + 0], v1 = row[8 * q + 1], v2 = row[8 * q + 2], v3 = row[8 * q + 3];
            float v4 = row[8 * q + 4], v5 = row[8 * q + 5], v6 = row[8 * q + 6], v7 = row[8 * q + 7];
            uint4 pk;
            pk.x = (unsigned)f2us(v0) | ((unsigned)f2us(v1) << 16);
            pk.y = (unsigned)f2us(v2) | ((unsigned)f2us(v3) << 16);
            pk.z = (unsigned)f2us(v4) | ((unsigned)f2us(v5) << 16);
            pk.w = (unsigned)f2us(v6) | ((unsigned)f2us(v7) << 16);
            *(uint4*)&hlb[gn * 32 + 8 * q] = pk;
        }
        {
            float4 h0 = *(const float4*)&row[32 + 8 * q];
            float4 h1 = *(const float4*)&row[32 + 8 * q + 4];
            *(float4*)&hr[gn * 32 + 8 * q] = h0;
            *(float4*)&hr[gn * 32 + 8 * q + 4] = h1;
        }
    }
}

// ---------------- Layer 2 agg (de-fused, r4 operating point: 16 nodes/block, no barriers) ----------------
// Edge-parallel, cooperative gather: 16 lanes/node = 4 edge slots x 4 channel-quarters.
__global__ __launch_bounds__(256) void k_l2_agg(const unsigned short* __restrict__ hlb, const float* __restrict__ hr,
                                                const float* __restrict__ att2, const float* __restrict__ b2,
                                                const int2* __restrict__ off2, const int* __restrict__ csr,
                                                float* __restrict__ x2, int N) {
    int tid = threadIdx.x;
    int node = blockIdx.x * 16 + (tid >> 4);
    if (node >= N) return;
    int sl = tid & 15;
    int g = sl & 3;
    int slot = sl >> 2;

    float hrq[8], atq[8];
    {
        const float4* h4 = (const float4*)(hr + (size_t)node * 32 + g * 8);
        float4 h0 = h4[0], h1 = h4[1];
        hrq[0] = h0.x; hrq[1] = h0.y; hrq[2] = h0.z; hrq[3] = h0.w;
        hrq[4] = h1.x; hrq[5] = h1.y; hrq[6] = h1.z; hrq[7] = h1.w;
        const float4* a4 = (const float4*)(att2 + g * 8);
        float4 a0 = a4[0], a1 = a4[1];
        atq[0] = a0.x; atq[1] = a0.y; atq[2] = a0.z; atq[3] = a0.w;
        atq[4] = a1.x; atq[5] = a1.y; atq[6] = a1.z; atq[7] = a1.w;
    }
    int2 ee = off2[node];

    float acc[8];
#pragma unroll
    for (int j = 0; j < 8; ++j) acc[j] = 0.f;
    float den = 0.f;

    int jj = ee.x + slot;
    int sN = (jj < ee.y) ? csr[jj] : node;
    uint4 uN = *(const uint4*)(hlb + (size_t)sN * 32 + g * 8);
    while (jj < ee.y) {
        uint4 u = uN;
        int jn = jj + 4;
        int s2 = (jn < ee.y) ? csr[jn] : node;
        uN = *(const uint4*)(hlb + (size_t)s2 * 32 + g * 8);
        unsigned uu[4] = {u.x, u.y, u.z, u.w};
        float hlv[8];
#pragma unroll
        for (int q = 0; q < 4; ++q) {
            hlv[2 * q]     = __uint_as_float(uu[q] << 16);
            hlv[2 * q + 1] = __uint_as_float(uu[q] & 0xFFFF0000u);
        }
        float t = 0.f;
#pragma unroll
        for (int j = 0; j < 8; ++j) {
            float e = hlv[j] + hrq[j];
            e = fmaxf(e, 0.2f * e);
            t += atq[j] * e;
        }
        t += __shfl_xor(t, 1);
        float w = __expf(t);
        den += w;
#pragma unroll
        for (int j = 0; j < 8; ++j) acc[j] += w * hlv[j];
        jj = jn;
    }

    if (slot == 0) {
        uint4 u = *(const uint4*)(hlb + (size_t)node * 32 + g * 8);
        unsigned uu[4] = {u.x, u.y, u.z, u.w};
        float hlv[8];
#pragma unroll
        for (int q = 0; q < 4; ++q) {
            hlv[2 * q]     = __uint_as_float(uu[q] << 16);
            hlv[2 * q + 1] = __uint_as_float(uu[q] & 0xFFFF0000u);
        }
        float t = 0.f;
#pragma unroll
        for (int j = 0; j < 8; ++j) {
            float e = hlv[j] + hrq[j];
            e = fmaxf(e, 0.2f * e);
            t += atq[j] * e;
        }
        t += __shfl_xor(t, 1);
        float w = __expf(t);
        den += w;
#pragma unroll
        for (int j = 0; j < 8; ++j) acc[j] += w * hlv[j];
    }

#pragma unroll
    for (int d = 4; d <= 8; d <<= 1) {
#pragma unroll
        for (int j = 0; j < 8; ++j) acc[j] += __shfl_xor(acc[j], d);
        den += __shfl_xor(den, d);
    }

    if (slot < 2) {
        float inv = 1.f / (den + 1e-16f);
        int c = g * 8 + slot * 4;
        float4 bb = *(const float4*)(b2 + c);
        float o0 = slot ? acc[4] : acc[0];
        float o1 = slot ? acc[5] : acc[1];
        float o2 = slot ? acc[6] : acc[2];
        float o3 = slot ? acc[7] : acc[3];
        *(float4*)&x2[(size_t)node * 32 + c] =
            make_float4(o0 * inv + bb.x, o1 * inv + bb.y, o2 * inv + bb.z, o3 * inv + bb.w);
    }
}

// ---------------- Layer 3 transform (standalone MFMA, r4 version) ----------------

__global__ __launch_bounds__(256) void k_l3_transform(const float* __restrict__ x2,
                                                      const unsigned short* __restrict__ Wp3h,
                                                      const unsigned short* __restrict__ Wp3l,
                                                      const float* __restrict__ bcat,
                                                      float* __restrict__ QS, unsigned short* __restrict__ KVb, int N) {
    __shared__ float xs[64 * 36];
    int t = threadIdx.x;
    int node0 = blockIdx.x * 64;
    int nrem = N - node0; if (nrem > 64) nrem = 64;
    const float4* xg = (const float4*)x2;
#pragma unroll
    for (int it = 0; it < 2; ++it) {
        int id = it * 256 + t;
        int row = id >> 3, c4 = id & 7;
        float4 v = make_float4(0.f, 0.f, 0.f, 0.f);
        if (row < nrem) v = xg[(size_t)(node0 + row) * 8 + c4];
        *(float4*)&xs[row * 36 + c4 * 4] = v;
    }
    __syncthreads();

    int w = t >> 6, lane = t & 63;
    int rowl = 16 * w + (lane & 15);
    int koff = (lane >> 4) * 8;

    bf16x8 xh, xl;
#pragma unroll
    for (int i = 0; i < 8; ++i) {
        float v = xs[rowl * 36 + koff + i];
        unsigned short hb = f2us(v);
        xh[i] = (short)hb;
        xl[i] = (short)f2us(v - us2f(hb));
    }

    const bf16x8* Wh = (const bf16x8*)Wp3h;
    const bf16x8* Wl = (const bf16x8*)Wp3l;
    f32x4 acc[2];
#pragma unroll
    for (int t3 = 0; t3 < 2; ++t3) {
        f32x4 a = {0.f, 0.f, 0.f, 0.f};
        bf16x8 wh = Wh[t3 * 64 + lane];
        bf16x8 wl = Wl[t3 * 64 + lane];
        a = __builtin_amdgcn_mfma_f32_16x16x32_bf16(xh, wh, a, 0, 0, 0);
        a = __builtin_amdgcn_mfma_f32_16x16x32_bf16(xl, wh, a, 0, 0, 0);
        a = __builtin_amdgcn_mfma_f32_16x16x32_bf16(xh, wl, a, 0, 0, 0);
        acc[t3] = a;
    }

    __syncthreads();
#pragma unroll
    for (int t3 = 0; t3 < 2; ++t3) {
        float bb = bcat[16 * t3 + (lane & 15)];
        int col = 16 * t3 + (lane & 15);
#pragma unroll
        for (int r = 0; r < 4; ++r) {
            int rowm = 16 * w + (lane >> 4) * 4 + r;
            xs[rowm * 36 + col] = acc[t3][r] + bb;
        }
    }
    __syncthreads();

    int node = t >> 2, q = t & 3;
    if (node < nrem) {
        size_t gn = node0 + node;
        const float* row = &xs[node * 36];
        if (q < 2) {
            float4 h0 = *(const float4*)&row[8 * q];
            float4 h1 = *(const float4*)&row[8 * q + 4];
            *(float4*)(QS + gn * 16 + 8 * q) = h0;
            *(float4*)(QS + gn * 16 + 8 * q + 4) = h1;
        } else {
            int qq = q - 2;
            float v0 = row[16 + 8 * qq + 0], v1 = row[16 + 8 * qq + 1];
            float v2 = row[16 + 8 * qq + 2], v3 = row[16 + 8 * qq + 3];
            float v4 = row[16 + 8 * qq + 4], v5 = row[16 + 8 * qq + 5];
            float v6 = row[16 + 8 * qq + 6], v7 = row[16 + 8 * qq + 7];
            uint4 pk;
            pk.x = (unsigned)f2us(v0) | ((unsigned)f2us(v1) << 16);
            pk.y = (unsigned)f2us(v2) | ((unsigned)f2us(v3) << 16);
            pk.z = (unsigned)f2us(v4) | ((unsigned)f2us(v5) << 16);
            pk.w = (unsigned)f2us(v6) | ((unsigned)f2us(v7) << 16);
            *(uint4*)&KVb[gn * 16 + 8 * qq] = pk;
        }
    }
}

// ---------------- Layer 3 agg: TransformerConv(32, 7, heads=1) ----------------
// Edge-parallel, pair-cooperative: 16 lanes/node = 8 edge slots x 2 sides; 2-deep prefetch.
__global__ __launch_bounds__(256) void k_l3_agg(const float* __restrict__ QS, const unsigned short* __restrict__ KVb,
                                                const int2* __restrict__ off2, const int* __restrict__ csr,
                                                float* __restrict__ out, int N) {
    int tid = threadIdx.x;
    int node = blockIdx.x * 16 + (tid >> 4);
    if (node >= N) return;
    int sl = tid & 15;
    int side = sl & 1;
    int p = sl >> 1;
    int lane = tid & 63;
    const float scale = 0.3779644730092272f;  // 1/sqrt(7)
    const float4* q4 = (const float4*)(QS + (size_t)node * 16);
    float4 qa = q4[0], qb = q4[1];
    qa.x *= scale; qa.y *= scale; qa.z *= scale; qa.w *= scale;
    qb.x *= scale; qb.y *= scale; qb.z *= scale; qb.w = 0.f;
    int2 ee = off2[node];

    float v[8];
#pragma unroll
    for (int i = 0; i < 8; ++i) v[i] = 0.f;

    int jj = ee.x + p;
    int sN = (jj < ee.y) ? csr[jj] : node;
    uint4 uN = *(const uint4*)(KVb + (size_t)sN * 16 + (side << 3));
    while (jj < ee.y) {
        uint4 u = uN;
        int jn = jj + 8;
        int s2 = (jn < ee.y) ? csr[jn] : node;
        uN = *(const uint4*)(KVb + (size_t)s2 * 16 + (side << 3));
        float t = 0.f;
        if (!side) {
            float k0 = __uint_as_float(u.x << 16), k1 = __uint_as_float(u.x & 0xFFFF0000u);
            float k2 = __uint_as_float(u.y << 16), k3 = __uint_as_float(u.y & 0xFFFF0000u);
            float k4 = __uint_as_float(u.z << 16), k5 = __uint_as_float(u.z & 0xFFFF0000u);
            float k6 = __uint_as_float(u.w << 16);
            t = qa.x * k0 + qa.y * k1 + qa.z * k2 + qa.w * k3
              + qb.x * k4 + qb.y * k5 + qb.z * k6;
        }
        float tf = __shfl_xor(t, 1);
        if (side) {
            float w = __expf(tf);
            v[0] += w * __uint_as_float(u.x << 16);
            v[1] += w * __uint_as_float(u.x & 0xFFFF0000u);
            v[2] += w * __uint_as_float(u.y << 16);
            v[3] += w * __uint_as_float(u.y & 0xFFFF0000u);
            v[4] += w * __uint_as_float(u.z << 16);
            v[5] += w * __uint_as_float(u.z & 0xFFFF0000u);
            v[6] += w * __uint_as_float(u.w << 16);
            v[7] += w;
        }
        jj = jn;
    }

#pragma unroll
    for (int d = 4; d >= 1; d >>= 1) {
#pragma unroll
        for (int i = 0; i < 8; ++i) {
            if (i < d) {
                float a = v[i], b = v[i + d];
                float send = (p & d) ? a : b;
                float recv = __shfl_xor(send, d << 1);
                v[i] = ((p & d) ? b : a) + recv;
            }
        }
    }
    float r = v[0];
    float den = __shfl(r, (lane & 48) | 15);
    if (side && p < 7) out[(size_t)node * 7 + p] = r / (den + 1e-16f)
                                                   + QS[(size_t)node * 16 + 8 + p];
}

// ---------------- launcher ----------------

extern "C" void kernel_launch(void* const* d_in, const int* in_sizes, int n_in,
                              void* d_out, int out_size, void* d_ws, size_t ws_size,
                              hipStream_t stream) {
    const int* ei = (const int*)d_in[1];
    float* out = (float*)d_out;

    int N = in_sizes[0] / 3;
    int E = in_sizes[1] / 2;
    int NB = (N + BMASK) >> BSH;        // assumed <= 512 (N <= 262144)
    int C = (E + NB - 1) / NB + 4096;

    char* ws = (char*)d_ws;
    size_t o = 0;
    auto take = [&](size_t bytes) -> char* {
        char* p = ws + o;
        o = (o + bytes + 255) & ~(size_t)255;
        return p;
    };
    int total_f = 0;
    for (int i = 2; i < 20; ++i) total_f += in_sizes[i];
    float* canon   = (float*)take((size_t)total_f * 4);
    unsigned short* Wp2h = (unsigned short*)take(4096 * 2);
    unsigned short* Wp2l = (unsigned short*)take(4096 * 2);
    unsigned short* Wp3h = (unsigned short*)take(1024 * 2);
    unsigned short* Wp3l = (unsigned short*)take(1024 * 2);
    float* bias64  = (float*)take(64 * 4);
    float* bcat    = (float*)take(32 * 4);
    float* Mfac    = (float*)take(32 * 4);
    int2*  off2    = (int2*)take((size_t)N * 8);
    int*   bcur    = (int*)take((512 * CUR_STRIDE + 1) * 4);
    int*   csr     = (int*)take((size_t)NB * C * 4);
    float* bufA    = (float*)take((size_t)N * 64 * 4);  // axs -> x2 | QS | KVb
    float* ad1     = (float*)take((size_t)N * 4 * 4);
    float* bufB    = (float*)take((size_t)N * 64 * 4);  // bkt -> hlb|hr
    (void)ws_size; (void)n_in; (void)out_size;

    CvtArgs ca;
    const float* cp[20];
    {
        int off_ = 0, k = 0;
        for (int i = 0; i < 20; ++i) {
            if (i < 2) { cp[i] = nullptr; continue; }
            ca.p[k] = d_in[i];
            ca.sz[k] = in_sizes[i];
            cp[i] = canon + off_;
            off_ += in_sizes[i];
            ++k;
        }
    }

    int nbconv = (total_f + 255) / 256;
    k_convert<<<nbconv + 1, 256, 0, stream>>>(ca, (const unsigned short*)d_in[0], canon, total_f,
                                              nbconv, Wp2h, Wp2l, Wp3h, Wp3l, bias64, bcat, Mfac, bcur);
    const int* flagp = bcur + 512 * CUR_STRIDE;

    // bkt aliases bufB; dead after k_bbuild_l1t, then bufB holds hlb|hr
    int* bkt = (int*)bufB;
    int gb = (E + 4095) / 4096;
    k_bscatter<<<gb, 1024, 0, stream>>>(ei, bcur, bkt, E, NB, C);

    float* axs = bufA;
    int nbl1 = (N + 511) >> 9;
    k_bbuild_l1t<<<NB + nbl1, 512, 0, stream>>>(bkt, bcur, off2, csr, d_in[0], flagp, Mfac,
                                                axs, ad1, N, NB, C);

    // fused l1_agg + l2_transform: reads axs (bufA), writes hlb|hr (bufB)
    unsigned short* hlb = (unsigned short*)bufB;                 // N*32 bf16 = 6.4 MB
    float* hr = bufB + (size_t)N * 16;                           // N*32 f32 = 12.8 MB
    k_l1agg_l2t<<<(N + 63) / 64, 256, 0, stream>>>(axs, (const float4*)ad1, off2, csr,
                                                   cp[2], cp[5], Wp2h, Wp2l, bias64, hlb, hr, N);

    // de-fused l2_agg (16 nodes/block): reads hlb|hr (bufB), writes x2 -> bufA (axs dead)
    float* x2 = bufA;                                            // N*32 f32 = 12.8 MB
    k_l2_agg<<<(N + 15) / 16, 256, 0, stream>>>(hlb, hr, cp[10], cp[11], off2, csr, x2, N);

    // standalone l3_transform: reads x2 (bufA), writes QS|KVb after x2 region (no overlap)
    float* QS = bufA + (size_t)N * 32;                           // N*16 f32 = 6.4 MB
    unsigned short* KVb = (unsigned short*)(bufA + (size_t)N * 48);  // N*16 bf16 = 3.2 MB
    k_l3_transform<<<(N + 63) / 64, 256, 0, stream>>>(x2, Wp3h, Wp3l, bcat, QS, KVb, N);

    k_l3_agg<<<(N + 15) / 16, 256, 0, stream>>>(QS, KVb, off2, csr, out, N);
}